// Round 9
// baseline (1223.840 us; speedup 1.0000x reference)
//
#include <hip/hip_runtime.h>

typedef _Float16 half8 __attribute__((ext_vector_type(8)));
typedef _Float16 half4 __attribute__((ext_vector_type(4)));
typedef float f32x4 __attribute__((ext_vector_type(4)));

__device__ __forceinline__ void gload_lds16(const void* g, void* l) {
  __builtin_amdgcn_global_load_lds((const __attribute__((address_space(1))) void*)g,
                                   (__attribute__((address_space(3))) void*)l, 16, 0, 0);
}

// ---------------- BN partial sums: grid 128 = (seg<<4 | c) ----------------
__global__ __launch_bounds__(256) void k_bn_partial(const float* __restrict__ x,
                                                    float* __restrict__ part) {
  const int c = blockIdx.x & 15;
  const int seg = blockIdx.x >> 4;
  const int t = threadIdx.x;
  float s = 0.f, s2 = 0.f;
  for (int b = 0; b < 32; ++b) {
    const float* row = x + (size_t)(b * 16 + c) * 4000 + seg * 500;
    for (int v = t; v < 500; v += 256) {
      float val = row[v];
      s += val;
      s2 += val * val;
    }
  }
#pragma unroll
  for (int off = 32; off > 0; off >>= 1) {
    s += __shfl_down(s, off);
    s2 += __shfl_down(s2, off);
  }
  __shared__ float rs_[4], rs2_[4];
  if ((t & 63) == 0) { rs_[t >> 6] = s; rs2_[t >> 6] = s2; }
  __syncthreads();
  if (t == 0) {
    part[c * 8 + seg] = rs_[0] + rs_[1] + rs_[2] + rs_[3];
    part[128 + c * 8 + seg] = rs2_[0] + rs2_[1] + rs2_[2] + rs2_[3];
  }
}

// ---------------- BN finalize ----------------
__global__ void k_bn_final(const float* __restrict__ part, float* __restrict__ musig) {
  const int c = threadIdx.x;
  if (c < 16) {
    float S = 0.f, S2 = 0.f;
#pragma unroll
    for (int seg = 0; seg < 8; ++seg) {
      S += part[c * 8 + seg];
      S2 += part[128 + c * 8 + seg];
    }
    const float inv = 1.f / 128000.f;
    float mu = S * inv;
    float var = S2 * inv - mu * mu;
    musig[c] = mu;
    musig[16 + c] = rsqrtf(var + 1e-5f);
  }
}

// ---------------- build x0 (normalized, permuted, transposed, scaled 1/16) ----------------
__global__ __launch_bounds__(256) void k_build_x0(const float* __restrict__ x,
                                                  const int* __restrict__ perm,
                                                  const float* __restrict__ musig,
                                                  _Float16* __restrict__ X0) {
  const int idx = blockIdx.x * 256 + threadIdx.x;
  const int v = idx & 4095;
  const int m = idx >> 12;
  const int b = m & 31;
  const int c = m >> 5;
  const int pv = perm[v];
  float val = 0.f;
  if (pv < 4000)
    val = (x[((size_t)(b * 16 + c)) * 4000 + pv] - musig[c]) * musig[16 + c] * 0.0625f;
  X0[idx] = (_Float16)val;
}

// ---------------- f32 -> f16 convert ----------------
__global__ __launch_bounds__(256) void k_cvt_f16(const float* __restrict__ s,
                                                 _Float16* __restrict__ d, int n) {
  const int i = (blockIdx.x * 256 + threadIdx.x) * 4;
  if (i >= n) return;
  f32x4 v = *(const f32x4*)(s + i);
  half4 h;
  h[0] = (_Float16)v[0]; h[1] = (_Float16)v[1];
  h[2] = (_Float16)v[2]; h[3] = (_Float16)v[3];
  *(half4*)(d + i) = h;
}

// ---------------- zero fill ----------------
__global__ __launch_bounds__(256) void k_zero(_Float16* __restrict__ p, int n8) {
  const int i = blockIdx.x * 256 + threadIdx.x;
  if (i < n8) *(half8*)(p + (size_t)i * 8) = half8{};
}

// ---------------- W permute+pad: Wp[f][k*CS + c] = W[f][c*25 + k] ----------------
__global__ __launch_bounds__(256) void k_prep_w(const float* __restrict__ W,
                                                _Float16* __restrict__ Wp,
                                                int F, int shiftC, int kround) {
  const int idx = blockIdx.x * 256 + threadIdx.x;
  const int CS = 1 << shiftC;
  const int KPtot = kround * CS;
  if (idx >= F * KPtot) return;
  const int f = idx / KPtot;
  const int rem = idx - f * KPtot;
  const int k = rem >> shiftC;
  const int c = rem & (CS - 1);
  float v = 0.f;
  if (k < 25) v = W[(size_t)f * (CS * 25) + c * 25 + k];
  Wp[idx] = (_Float16)v;
}

// ---------------- Chebyshev conv1 partial GEMM: 256x256 tile, BK=32, 3-buf ----------------
// P[kq][m][v] = sum_{u in kq K-slice(512)} Xprev[m][u] * L[v][u]
// M=512, V=4096. Grid 256: kq = bid&7 (XCD-resident B slice, 4MB L2),
// bx = (bid>>3)&15, by = bid>>7. 512 thr = 8 waves (2m x 4v), wave 128x64
// (8x4 frags). BK=32 -> 64B LDS rows; swizzle slot c8 ^ ((row>>1)&3) gives a
// bijective (ln,g)->16B-slot map per 16-row group (conflict-free b128 reads).
// 3-buf (3x32KB), 2-ahead, counted vmcnt(4); one phase per K-tile:
// {12 ds_read | stage 4 | vmcnt(4) | barrier | lgkm+sched_barrier | 32 MFMA | barrier}.
__global__ __launch_bounds__(512, 1) void k_cheb1(const _Float16* __restrict__ Xprev,
                                                  const _Float16* __restrict__ Lm,
                                                  _Float16* __restrict__ P) {
  __shared__ _Float16 lds[3][16384];  // [buf][A: 256x32 halfs | B: 256x32 halfs]
  const int t = threadIdx.x;
  const int lane = t & 63;
  const int ln = lane & 15;
  const int g = lane >> 4;
  const int w = t >> 6;
  const int wm = w >> 2, wn = w & 3;
  const int bid = blockIdx.x;
  const int kq = bid & 7;
  const int bx = (bid >> 3) & 15;
  const int by = bid >> 7;
  const int v0 = bx * 256, m0 = by * 256;
  const size_t rs = 8192;  // 4096 * 2B

  const char* Ag = (const char*)Xprev + (size_t)m0 * rs + kq * 1024;
  const char* Bg = (const char*)Lm + (size_t)v0 * rs + kq * 1024;

  f32x4 acc[8][4] = {};

  auto stage = [&](int buf, int tt) {  // 4 gload_lds / thread
    char* A = (char*)&lds[buf][0];
    char* B = (char*)&lds[buf][8192];
#pragma unroll
    for (int j = 0; j < 2; ++j) {
      const int ch = j * 512 + t;          // 0..1023 chunks (256 rows x 4 slots)
      const int row = ch >> 2, c8 = ch & 3;
      const size_t so = (size_t)row * rs + tt * 64 + ((c8 ^ ((row >> 1) & 3)) << 4);
      gload_lds16(Ag + so, A + ch * 16);
      gload_lds16(Bg + so, B + ch * 16);
    }
  };

  // prologue: T0, T1 staged; wait T0 (T1's 4 still in flight)
  stage(0, 0);
  stage(1, 1);
  asm volatile("s_waitcnt vmcnt(4)" ::: "memory");
  asm volatile("s_barrier" ::: "memory");

  for (int tt = 0; tt < 16; ++tt) {
    const int cur = tt % 3;
    const char* A = (const char*)&lds[cur][0];
    const char* B = A + 16384;
    half8 a[8], b[4];
#pragma unroll
    for (int mi = 0; mi < 8; ++mi) {
      const int ar = wm * 128 + mi * 16 + ln;
      a[mi] = *(const half8*)(A + ar * 64 + (((g ^ ((ar >> 1) & 3))) << 4));
    }
#pragma unroll
    for (int ni = 0; ni < 4; ++ni) {
      const int br = wn * 64 + ni * 16 + ln;
      b[ni] = *(const half8*)(B + br * 64 + (((g ^ ((br >> 1) & 3))) << 4));
    }
    if (tt + 2 < 16) {
      stage((tt + 2) % 3, tt + 2);
      asm volatile("s_waitcnt vmcnt(4)" ::: "memory");  // T+1 landed, T+2 in flight
    } else {
      asm volatile("s_waitcnt vmcnt(0)" ::: "memory");  // tail drain
    }
    asm volatile("s_barrier" ::: "memory");
    asm volatile("s_waitcnt lgkmcnt(0)" ::: "memory");
    __builtin_amdgcn_sched_barrier(0);
    __builtin_amdgcn_s_setprio(1);
#pragma unroll
    for (int mi = 0; mi < 8; ++mi)
#pragma unroll
      for (int ni = 0; ni < 4; ++ni)
        acc[mi][ni] = __builtin_amdgcn_mfma_f32_16x16x32_f16(a[mi], b[ni], acc[mi][ni], 0, 0, 0);
    __builtin_amdgcn_s_setprio(0);
    asm volatile("s_barrier" ::: "memory");
  }

  // epilogue: write fp16 partial plane kq
  _Float16* Pq = P + (size_t)kq * 2097152;
#pragma unroll
  for (int mi = 0; mi < 8; ++mi) {
#pragma unroll
    for (int ni = 0; ni < 4; ++ni) {
      const int vv = v0 + wn * 64 + ni * 16 + ln;
      const int mmb = m0 + wm * 128 + mi * 16 + g * 4;
#pragma unroll
      for (int r = 0; r < 4; ++r)
        Pq[(size_t)(mmb + r) * 4096 + vv] = (_Float16)acc[mi][ni][r];
    }
  }
}

// ---------------- reduce 8 partials: Xout = alpha*sum(P) - beta*Xm2 ----------------
__global__ __launch_bounds__(256) void k_cheb_red8(const _Float16* __restrict__ P,
                                                   const _Float16* __restrict__ Xm2,
                                                   _Float16* __restrict__ Xout,
                                                   float alpha, float beta) {
  const size_t i = ((size_t)blockIdx.x * 256 + threadIdx.x) * 8;
  float s[8] = {};
#pragma unroll
  for (int p = 0; p < 8; ++p) {
    half8 v = *(const half8*)(P + (size_t)p * 2097152 + i);
#pragma unroll
    for (int j = 0; j < 8; ++j) s[j] += (float)v[j];
  }
  half8 xm2 = {};
  if (beta != 0.f) xm2 = *(const half8*)(Xm2 + i);
  half8 o;
#pragma unroll
  for (int j = 0; j < 8; ++j) o[j] = (_Float16)(alpha * s[j] - beta * (float)xm2[j]);
  *(half8*)(Xout + i) = o;
}

// ---------------- Chebyshev conv2: fused full-K GEMM (R8, unchanged) ----------------
__global__ __launch_bounds__(256, 2) void k_cheb2(const _Float16* __restrict__ Xprev,
                                                  const _Float16* __restrict__ Lm,
                                                  const _Float16* __restrict__ Xm2,
                                                  _Float16* __restrict__ Xout,
                                                  float alpha, float beta) {
  __shared__ _Float16 lds[3][8192];  // [buf][A:64x64 (8KB) | B:64x64 (8KB)]
  const int t = threadIdx.x;
  const int lane = t & 63;
  const int ln = lane & 15;
  const int g = lane >> 4;
  const int g16 = g << 4;
  const int w = t >> 6;
  const int wm = w >> 1, wn = w & 1;
  const int bx = blockIdx.x & 15;
  const int by = blockIdx.x >> 4;
  const int v0 = bx * 64, m0 = by * 64;
  const size_t rs = 2048;  // 1024 * 2B

  const char* Ag = (const char*)Xprev + (size_t)m0 * rs;
  const char* Bg = (const char*)Lm + (size_t)v0 * rs;

  f32x4 acc[2][2] = {};

  auto stageHalf = [&](int buf, int tt, int half) {  // 2 gload_lds / thread
    const char* src = (half == 0) ? Ag : Bg;
    char* dst0 = (char*)&lds[buf][0] + half * 8192;
#pragma unroll
    for (int j = 0; j < 2; ++j) {
      const int idx = j * 256 + t;
      const int row = idx >> 3, c8 = idx & 7;
      gload_lds16(src + (size_t)row * rs + tt * 128 + ((c8 ^ (row & 7)) << 4),
                  dst0 + idx * 16);
    }
  };

  stageHalf(0, 0, 0); stageHalf(0, 0, 1);
  stageHalf(1, 1, 0); stageHalf(1, 1, 1);
  asm volatile("s_waitcnt vmcnt(4)" ::: "memory");
  asm volatile("s_barrier" ::: "memory");

  for (int tt = 0; tt < 16; ++tt) {
    const int cur = tt % 3;
    const int nxt = (tt + 2) % 3;
    const char* A = (const char*)&lds[cur][0];
    const char* B = A + 8192;
    half8 a[2][2], b[2][2];
#pragma unroll
    for (int kk = 0; kk < 2; ++kk) {
#pragma unroll
      for (int mi = 0; mi < 2; ++mi) {
        const int ar = wm * 32 + mi * 16 + ln;
        a[kk][mi] = *(const half8*)(A + ar * 128 + ((kk * 64 + g16) ^ ((ar & 7) << 4)));
      }
#pragma unroll
      for (int ni = 0; ni < 2; ++ni) {
        const int br = wn * 32 + ni * 16 + ln;
        b[kk][ni] = *(const half8*)(B + br * 128 + ((kk * 64 + g16) ^ ((br & 7) << 4)));
      }
    }
    if (tt + 2 < 16) {
      stageHalf(nxt, tt + 2, 0);
      stageHalf(nxt, tt + 2, 1);
      asm volatile("s_waitcnt vmcnt(4)" ::: "memory");
    } else {
      asm volatile("s_waitcnt vmcnt(0)" ::: "memory");
    }
    asm volatile("s_barrier" ::: "memory");
    asm volatile("s_waitcnt lgkmcnt(0)" ::: "memory");
    __builtin_amdgcn_sched_barrier(0);
    __builtin_amdgcn_s_setprio(1);
#pragma unroll
    for (int kk = 0; kk < 2; ++kk)
#pragma unroll
      for (int mi = 0; mi < 2; ++mi)
#pragma unroll
        for (int ni = 0; ni < 2; ++ni)
          acc[mi][ni] = __builtin_amdgcn_mfma_f32_16x16x32_f16(a[kk][mi], b[kk][ni],
                                                               acc[mi][ni], 0, 0, 0);
    __builtin_amdgcn_s_setprio(0);
    asm volatile("s_barrier" ::: "memory");
  }

#pragma unroll
  for (int mi = 0; mi < 2; ++mi) {
#pragma unroll
    for (int ni = 0; ni < 2; ++ni) {
      const int vv = v0 + wn * 32 + ni * 16 + ln;
      const int mmb = m0 + wm * 32 + mi * 16 + g * 4;
#pragma unroll
      for (int r = 0; r < 4; ++r) {
        const size_t idx = (size_t)(mmb + r) * 1024 + vv;
        float val = alpha * acc[mi][ni][r];
        if (beta != 0.f) val -= (float)Xm2[idx];
        Xout[idx] = (_Float16)val;
      }
    }
  }
}

// ---------------- Dense projection GEMM, gload_lds + counted vmcnt ----------------
template <int FT>
__global__ __launch_bounds__(256, 2) void k_dense(const _Float16* __restrict__ Wp,
                                                  const _Float16* __restrict__ XS,
                                                  const float* __restrict__ bias,
                                                  float* __restrict__ Yt,
                                                  int Vv, int shiftC, int nsteps,
                                                  int Ntot, float ascale, float bscale) {
  __shared__ _Float16 Alds[2][FT * 64];
  __shared__ _Float16 Blds[2][64 * 64];
  const int t = threadIdx.x;
  const int lane = t & 63;
  const int g = lane >> 4;
  const int w = t >> 6;
  const int n0 = blockIdx.x * 64;
  const int b = n0 / Vv;
  const int vb = n0 % Vv;
  const int Kp = nsteps * 64;
  const int cmask = (1 << shiftC) - 1;
  const size_t plane = 2097152;

  f32x4 acc[FT / 16] = {};

  auto stage = [&](int buf, int s) {
    const int q0 = s * 64;
    char* A = (char*)&Alds[buf][0];
    char* B = (char*)&Blds[buf][0];
#pragma unroll
    for (int j = 0; j < FT / 32; ++j) {
      const int ch = j * 256 + t;
      const int f = ch >> 3, c8 = ch & 7;
      gload_lds16((const char*)Wp + ((size_t)f * Kp + q0) * 2 + ((c8 ^ (f & 7)) << 4),
                  A + ch * 16);
    }
#pragma unroll
    for (int j = 0; j < 2; ++j) {
      const int ch = j * 256 + t;
      const int q = ch >> 3, c8 = ch & 7;
      const int qq = q0 + q;
      const int k = qq >> shiftC, c = qq & cmask;
      const int sz = (q >> 3) & 7;
      gload_lds16((const char*)XS + ((size_t)k * plane + (size_t)(c * 32 + b) * Vv + vb) * 2 +
                      ((c8 ^ sz) << 4),
                  B + ch * 16);
    }
  };

  stage(0, 0);

  for (int s = 0; s < nsteps; ++s) {
    const int cur = s & 1;
    if (s + 1 < nsteps) {
      stage(cur ^ 1, s + 1);
      if constexpr (FT == 64) {
        asm volatile("s_waitcnt vmcnt(4)" ::: "memory");
      } else {
        asm volatile("s_waitcnt vmcnt(6)" ::: "memory");
      }
    } else {
      asm volatile("s_waitcnt vmcnt(0)" ::: "memory");
    }
    asm volatile("s_barrier" ::: "memory");
    const _Float16* A = &Alds[cur][0];
    const _Float16* B = &Blds[cur][0];
#pragma unroll
    for (int kk = 0; kk < 2; ++kk) {
      half8 bf;
      const int c = lane & 15;
#pragma unroll
      for (int j = 0; j < 8; ++j) {
        const int q = kk * 32 + g * 8 + j;
        const int sz = (q >> 3) & 7;
        bf[j] = B[q * 64 + ((w * 16 + c) ^ (sz << 3))];
      }
#pragma unroll
      for (int mi = 0; mi < FT / 16; ++mi) {
        const int ar = mi * 16 + c;
        half8 af = *(const half8*)((const char*)A + ar * 128 +
                                   ((kk * 64 + g * 16) ^ ((ar & 7) << 4)));
        acc[mi] = __builtin_amdgcn_mfma_f32_16x16x32_f16(af, bf, acc[mi], 0, 0, 0);
      }
    }
    asm volatile("s_barrier" ::: "memory");
  }

  const int n = n0 + w * 16 + (lane & 15);
#pragma unroll
  for (int mi = 0; mi < FT / 16; ++mi) {
#pragma unroll
    for (int r = 0; r < 4; ++r) {
      const int f = mi * 16 + g * 4 + r;
      Yt[(size_t)f * Ntot + n] = fmaxf(ascale * acc[mi][r] + bscale * bias[f], 0.f);
    }
  }
}

// ---------------- pool1 ----------------
__global__ __launch_bounds__(256) void k_pool1(const float* __restrict__ Yt,
                                               _Float16* __restrict__ X2) {
  const int idx = blockIdx.x * 256 + threadIdx.x;
  const int v2 = idx & 1023;
  const int rest = idx >> 10;
  const int b = rest & 31;
  const int f = rest >> 5;
  f32x4 q = *(const f32x4*)(Yt + (size_t)f * 131072 + b * 4096 + v2 * 4);
  float mx = fmaxf(fmaxf(q[0], q[1]), fmaxf(q[2], q[3]));
  X2[(size_t)(f * 32 + b) * 1024 + v2] = (_Float16)(mx * 0.015625f);
}

// ---------------- pool2 ----------------
__global__ __launch_bounds__(256) void k_pool2(const float* __restrict__ Yt,
                                               float* __restrict__ p2) {
  const int idx = blockIdx.x * 256 + threadIdx.x;
  const int v3 = idx & 255;
  const int rest = idx >> 8;
  const int f = rest & 127;
  const int b = rest >> 7;
  f32x4 q = *(const f32x4*)(Yt + (size_t)f * 32768 + b * 1024 + v3 * 4);
  float mx = fmaxf(fmaxf(q[0], q[1]), fmaxf(q[2], q[3]));
  p2[(size_t)b * 32768 + f * 256 + v3] = mx;
}

// ---------------- FC pass 1 ----------------
__global__ __launch_bounds__(256) void k_fc_part(const float* __restrict__ p2,
                                                 const float* __restrict__ Wfc,
                                                 float* __restrict__ partF) {
  const int b = blockIdx.x >> 3;
  const int seg = blockIdx.x & 7;
  const int t = threadIdx.x;
  const int lane = t & 63;
  const int w = t >> 6;
  const int base = seg * 4096;
  float acc[10];
#pragma unroll
  for (int o = 0; o < 10; ++o) acc[o] = 0.f;
  const float* pb = p2 + (size_t)b * 32768 + base;
  for (int i = t; i < 4096; i += 256) {
    float p = pb[i];
#pragma unroll
    for (int o = 0; o < 10; ++o) acc[o] += p * Wfc[(size_t)o * 32768 + base + i];
  }
#pragma unroll
  for (int off = 32; off > 0; off >>= 1)
#pragma unroll
    for (int o = 0; o < 10; ++o) acc[o] += __shfl_down(acc[o], off);
  __shared__ float rws[10][4];
  if (lane == 0) {
#pragma unroll
    for (int o = 0; o < 10; ++o) rws[o][w] = acc[o];
  }
  __syncthreads();
  if (t < 10) partF[blockIdx.x * 10 + t] =
      rws[t][0] + rws[t][1] + rws[t][2] + rws[t][3];
}

// ---------------- FC pass 2 ----------------
__global__ void k_fc_final(const float* __restrict__ partF,
                           const float* __restrict__ bfc,
                           float* __restrict__ out) {
  const int t = threadIdx.x;
  if (t < 320) {
    const int b = t / 10, o = t - b * 10;
    float s = 0.f;
#pragma unroll
    for (int seg = 0; seg < 8; ++seg) s += partF[(b * 8 + seg) * 10 + o];
    out[b * 10 + o] = 64.f * s + bfc[o];
  }
}

extern "C" void kernel_launch(void* const* d_in, const int* in_sizes, int n_in,
                              void* d_out, int out_size, void* d_ws, size_t ws_size,
                              hipStream_t stream) {
  (void)in_sizes; (void)n_in; (void)out_size; (void)ws_size;
  const float* x = (const float*)d_in[0];
  const int* perm = (const int*)d_in[1];
  const float* L1 = (const float*)d_in[2];
  const float* L2 = (const float*)d_in[3];
  const float* W1 = (const float*)d_in[4];
  const float* b1 = (const float*)d_in[5];
  const float* W2 = (const float*)d_in[6];
  const float* b2 = (const float*)d_in[7];
  const float* Wfc = (const float*)d_in[8];
  const float* bfc = (const float*)d_in[9];
  float* out = (float*)d_out;

  char* ws = (char*)d_ws;
  size_t off = 0;
  auto alloc = [&](size_t bytes) {
    char* p = ws + off;
    off += (bytes + 255) & ~(size_t)255;
    return p;
  };
  _Float16* L1h = (_Float16*)alloc(16777216ull * 2);
  _Float16* L2h = (_Float16*)alloc(1048576ull * 2);
  _Float16* W1p = (_Float16*)alloc(64ull * 448 * 2);
  _Float16* W2p = (_Float16*)alloc(128ull * 1664 * 2);
  float* part = (float*)alloc(256 * 4);
  float* musig = (float*)alloc(32 * 4);
  float* partF = (float*)alloc(2560 * 4);
  _Float16* XS = (_Float16*)alloc(28ull * 2097152 * 2);   // 25 states + 3 zero planes
  float* Yt = (float*)alloc(64ull * 131072 * 4);          // 32MB; aliased as Pq during conv1
  float* p2 = (float*)alloc(32ull * 128 * 256 * 4);
  _Float16* Pq = (_Float16*)Yt;  // 8 partial planes (32MB), dead before dense1 writes Yt

  const size_t plane = 2097152;

  k_cvt_f16<<<16384, 256, 0, stream>>>(L1, L1h, 16777216);
  k_cvt_f16<<<1024, 256, 0, stream>>>(L2, L2h, 1048576);
  k_prep_w<<<112, 256, 0, stream>>>(W1, W1p, 64, 4, 28);
  k_prep_w<<<832, 256, 0, stream>>>(W2, W2p, 128, 6, 26);
  k_zero<<<3072, 256, 0, stream>>>(XS + 25 * plane, 786432);
  k_bn_partial<<<128, 256, 0, stream>>>(x, part);
  k_bn_final<<<1, 64, 0, stream>>>(part, musig);
  k_build_x0<<<8192, 256, 0, stream>>>(x, perm, musig, XS);

  // conv1: grid 256 = kq8 (fastest, XCD-resident) x bx16 x by2, K-slice 512
  for (int k = 1; k < 25; ++k) {
    k_cheb1<<<256, 512, 0, stream>>>(XS + (size_t)(k - 1) * plane, L1h, Pq);
    k_cheb_red8<<<1024, 256, 0, stream>>>(
        Pq, XS + (size_t)(k >= 2 ? k - 2 : 0) * plane, XS + (size_t)k * plane,
        (k == 1) ? 1.f : 2.f, (k == 1) ? 0.f : 1.f);
  }
  k_dense<64><<<dim3(2048, 1), 256, 0, stream>>>(W1p, XS, b1, Yt, 4096, 4, 7,
                                                 131072, 16.f, 1.f);
  k_pool1<<<8192, 256, 0, stream>>>(Yt, XS);
  // conv2: fused full-K kernel, grid 512 = by32 x bx16, 2 blocks/CU
  for (int k = 1; k < 25; ++k) {
    k_cheb2<<<512, 256, 0, stream>>>(
        XS + (size_t)(k - 1) * plane, L2h,
        XS + (size_t)(k >= 2 ? k - 2 : 0) * plane, XS + (size_t)k * plane,
        (k == 1) ? 1.f : 2.f, (k == 1) ? 0.f : 1.f);
  }
  k_dense<128><<<dim3(512, 1), 256, 0, stream>>>(W2p, XS, b2, Yt, 1024, 6, 26,
                                                 32768, 1.f, 0.015625f);
  k_pool2<<<4096, 256, 0, stream>>>(Yt, p2);
  k_fc_part<<<256, 256, 0, stream>>>(p2, Wfc, partF);
  k_fc_final<<<1, 320, 0, stream>>>(partF, bfc, out);
}

// Round 12
// 1222.585 us; speedup vs baseline: 1.0010x; 1.0010x over previous
//
#include <hip/hip_runtime.h>

typedef _Float16 half8 __attribute__((ext_vector_type(8)));
typedef _Float16 half4 __attribute__((ext_vector_type(4)));
typedef float f32x4 __attribute__((ext_vector_type(4)));

__device__ __forceinline__ void gload_lds16(const void* g, void* l) {
  __builtin_amdgcn_global_load_lds((const __attribute__((address_space(1))) void*)g,
                                   (__attribute__((address_space(3))) void*)l, 16, 0, 0);
}

// ---------------- BN partial sums: grid 128 = (seg<<4 | c) ----------------
__global__ __launch_bounds__(256) void k_bn_partial(const float* __restrict__ x,
                                                    float* __restrict__ part) {
  const int c = blockIdx.x & 15;
  const int seg = blockIdx.x >> 4;
  const int t = threadIdx.x;
  float s = 0.f, s2 = 0.f;
  for (int b = 0; b < 32; ++b) {
    const float* row = x + (size_t)(b * 16 + c) * 4000 + seg * 500;
    for (int v = t; v < 500; v += 256) {
      float val = row[v];
      s += val;
      s2 += val * val;
    }
  }
#pragma unroll
  for (int off = 32; off > 0; off >>= 1) {
    s += __shfl_down(s, off);
    s2 += __shfl_down(s2, off);
  }
  __shared__ float rs_[4], rs2_[4];
  if ((t & 63) == 0) { rs_[t >> 6] = s; rs2_[t >> 6] = s2; }
  __syncthreads();
  if (t == 0) {
    part[c * 8 + seg] = rs_[0] + rs_[1] + rs_[2] + rs_[3];
    part[128 + c * 8 + seg] = rs2_[0] + rs2_[1] + rs2_[2] + rs2_[3];
  }
}

// ---------------- BN finalize ----------------
__global__ void k_bn_final(const float* __restrict__ part, float* __restrict__ musig) {
  const int c = threadIdx.x;
  if (c < 16) {
    float S = 0.f, S2 = 0.f;
#pragma unroll
    for (int seg = 0; seg < 8; ++seg) {
      S += part[c * 8 + seg];
      S2 += part[128 + c * 8 + seg];
    }
    const float inv = 1.f / 128000.f;
    float mu = S * inv;
    float var = S2 * inv - mu * mu;
    musig[c] = mu;
    musig[16 + c] = rsqrtf(var + 1e-5f);
  }
}

// ---------------- build x0 (normalized, permuted, transposed, scaled 1/16) ----------------
__global__ __launch_bounds__(256) void k_build_x0(const float* __restrict__ x,
                                                  const int* __restrict__ perm,
                                                  const float* __restrict__ musig,
                                                  _Float16* __restrict__ X0) {
  const int idx = blockIdx.x * 256 + threadIdx.x;
  const int v = idx & 4095;
  const int m = idx >> 12;
  const int b = m & 31;
  const int c = m >> 5;
  const int pv = perm[v];
  float val = 0.f;
  if (pv < 4000)
    val = (x[((size_t)(b * 16 + c)) * 4000 + pv] - musig[c]) * musig[16 + c] * 0.0625f;
  X0[idx] = (_Float16)val;
}

// ---------------- f32 -> f16 convert ----------------
__global__ __launch_bounds__(256) void k_cvt_f16(const float* __restrict__ s,
                                                 _Float16* __restrict__ d, int n) {
  const int i = (blockIdx.x * 256 + threadIdx.x) * 4;
  if (i >= n) return;
  f32x4 v = *(const f32x4*)(s + i);
  half4 h;
  h[0] = (_Float16)v[0]; h[1] = (_Float16)v[1];
  h[2] = (_Float16)v[2]; h[3] = (_Float16)v[3];
  *(half4*)(d + i) = h;
}

// ---------------- zero fill ----------------
__global__ __launch_bounds__(256) void k_zero(_Float16* __restrict__ p, int n8) {
  const int i = blockIdx.x * 256 + threadIdx.x;
  if (i < n8) *(half8*)(p + (size_t)i * 8) = half8{};
}

// ---------------- W permute+pad: Wp[f][k*CS + c] = W[f][c*25 + k] ----------------
__global__ __launch_bounds__(256) void k_prep_w(const float* __restrict__ W,
                                                _Float16* __restrict__ Wp,
                                                int F, int shiftC, int kround) {
  const int idx = blockIdx.x * 256 + threadIdx.x;
  const int CS = 1 << shiftC;
  const int KPtot = kround * CS;
  if (idx >= F * KPtot) return;
  const int f = idx / KPtot;
  const int rem = idx - f * KPtot;
  const int k = rem >> shiftC;
  const int c = rem & (CS - 1);
  float v = 0.f;
  if (k < 25) v = W[(size_t)f * (CS * 25) + c * 25 + k];
  Wp[idx] = (_Float16)v;
}

// ---------------- Chebyshev conv1 partial GEMM: 256x256, BK=32, m201-style phases ----------------
// P[kq][m][v] = sum_{u in kq K-slice(512)} Xprev[m][u] * L[v][u]
// Grid 256 = kq8 (XCD-resident) x bx16 x by2. 512 thr = 8 waves (2m x 4v),
// wave 128x64 (8x4 frags). 3-buf (3x32KB), 2-ahead, counted vmcnt(4).
// Per K-tile, TWO phases of 16 MFMA each (m201 granularity):
//  P0: {8 ds_read (a0-3,b0-3) | 2 gload | bar | lgkm+SB | 16 MFMA mi0-3 | bar}
//  P1: {4 ds_read (a4-7)      | 2 gload + vmcnt(4) | bar | lgkm+SB | 16 MFMA mi4-7 | bar}
// Staging/swizzle identical to R9 (verified: 2-way banks, correct).
__global__ __launch_bounds__(512, 1) void k_cheb1(const _Float16* __restrict__ Xprev,
                                                  const _Float16* __restrict__ Lm,
                                                  _Float16* __restrict__ P) {
  __shared__ _Float16 lds[3][16384];  // [buf][A: 256x32 | B: 256x32]
  const int t = threadIdx.x;
  const int lane = t & 63;
  const int ln = lane & 15;
  const int g = lane >> 4;
  const int w = t >> 6;
  const int wm = w >> 2, wn = w & 3;
  const int bid = blockIdx.x;
  const int kq = bid & 7;
  const int bx = (bid >> 3) & 15;
  const int by = bid >> 7;
  const int v0 = bx * 256, m0 = by * 256;
  const size_t rs = 8192;  // 4096 * 2B

  const char* Ag = (const char*)Xprev + (size_t)m0 * rs + kq * 1024;
  const char* Bg = (const char*)Lm + (size_t)v0 * rs + kq * 1024;

  f32x4 acc[8][4] = {};

  auto stageHalf = [&](int buf, int tt, int h) {  // 2 gload_lds / thread
    char* A = (char*)&lds[buf][0];
    char* B = (char*)&lds[buf][8192];
    const int ch = h * 512 + t;          // 0..1023 chunks (256 rows x 4 slots)
    const int row = ch >> 2, c8 = ch & 3;
    const size_t so = (size_t)row * rs + tt * 64 + ((c8 ^ ((row >> 1) & 3)) << 4);
    gload_lds16(Ag + so, A + ch * 16);
    gload_lds16(Bg + so, B + ch * 16);
  };

  // prologue: T0, T1 staged; wait T0 (T1's 4 still in flight)
  stageHalf(0, 0, 0); stageHalf(0, 0, 1);
  stageHalf(1, 1, 0); stageHalf(1, 1, 1);
  asm volatile("s_waitcnt vmcnt(4)" ::: "memory");
  asm volatile("s_barrier" ::: "memory");

  for (int tt = 0; tt < 16; ++tt) {
    const int cur = tt % 3;
    const int nxt = (tt + 2) % 3;
    const char* A = (const char*)&lds[cur][0];
    const char* B = A + 16384;
    half8 a[8], b[4];

    // ---- phase 0: a0-3, b0-3 -> 16 MFMA (mi 0..3) ----
#pragma unroll
    for (int mi = 0; mi < 4; ++mi) {
      const int ar = wm * 128 + mi * 16 + ln;
      a[mi] = *(const half8*)(A + ar * 64 + ((g ^ ((ar >> 1) & 3)) << 4));
    }
#pragma unroll
    for (int ni = 0; ni < 4; ++ni) {
      const int br = wn * 64 + ni * 16 + ln;
      b[ni] = *(const half8*)(B + br * 64 + ((g ^ ((br >> 1) & 3)) << 4));
    }
    if (tt + 2 < 16) stageHalf(nxt, tt + 2, 0);
    asm volatile("s_barrier" ::: "memory");
    asm volatile("s_waitcnt lgkmcnt(0)" ::: "memory");
    __builtin_amdgcn_sched_barrier(0);
    __builtin_amdgcn_s_setprio(1);
#pragma unroll
    for (int mi = 0; mi < 4; ++mi)
#pragma unroll
      for (int ni = 0; ni < 4; ++ni)
        acc[mi][ni] = __builtin_amdgcn_mfma_f32_16x16x32_f16(a[mi], b[ni], acc[mi][ni], 0, 0, 0);
    __builtin_amdgcn_s_setprio(0);
    asm volatile("s_barrier" ::: "memory");

    // ---- phase 1: a4-7 (b reused) -> 16 MFMA (mi 4..7) ----
#pragma unroll
    for (int mi = 4; mi < 8; ++mi) {
      const int ar = wm * 128 + mi * 16 + ln;
      a[mi] = *(const half8*)(A + ar * 64 + ((g ^ ((ar >> 1) & 3)) << 4));
    }
    if (tt + 2 < 16) {
      stageHalf(nxt, tt + 2, 1);
      asm volatile("s_waitcnt vmcnt(4)" ::: "memory");  // T+1 landed, T+2 in flight
    } else {
      asm volatile("s_waitcnt vmcnt(0)" ::: "memory");  // tail drain
    }
    asm volatile("s_barrier" ::: "memory");
    asm volatile("s_waitcnt lgkmcnt(0)" ::: "memory");
    __builtin_amdgcn_sched_barrier(0);
    __builtin_amdgcn_s_setprio(1);
#pragma unroll
    for (int mi = 4; mi < 8; ++mi)
#pragma unroll
      for (int ni = 0; ni < 4; ++ni)
        acc[mi][ni] = __builtin_amdgcn_mfma_f32_16x16x32_f16(a[mi], b[ni], acc[mi][ni], 0, 0, 0);
    __builtin_amdgcn_s_setprio(0);
    asm volatile("s_barrier" ::: "memory");
  }

  // epilogue: write fp16 partial plane kq
  _Float16* Pq = P + (size_t)kq * 2097152;
#pragma unroll
  for (int mi = 0; mi < 8; ++mi) {
#pragma unroll
    for (int ni = 0; ni < 4; ++ni) {
      const int vv = v0 + wn * 64 + ni * 16 + ln;
      const int mmb = m0 + wm * 128 + mi * 16 + g * 4;
#pragma unroll
      for (int r = 0; r < 4; ++r)
        Pq[(size_t)(mmb + r) * 4096 + vv] = (_Float16)acc[mi][ni][r];
    }
  }
}

// ---------------- reduce 8 partials: Xout = alpha*sum(P) - beta*Xm2 ----------------
__global__ __launch_bounds__(256) void k_cheb_red8(const _Float16* __restrict__ P,
                                                   const _Float16* __restrict__ Xm2,
                                                   _Float16* __restrict__ Xout,
                                                   float alpha, float beta) {
  const size_t i = ((size_t)blockIdx.x * 256 + threadIdx.x) * 8;
  float s[8] = {};
#pragma unroll
  for (int p = 0; p < 8; ++p) {
    half8 v = *(const half8*)(P + (size_t)p * 2097152 + i);
#pragma unroll
    for (int j = 0; j < 8; ++j) s[j] += (float)v[j];
  }
  half8 xm2 = {};
  if (beta != 0.f) xm2 = *(const half8*)(Xm2 + i);
  half8 o;
#pragma unroll
  for (int j = 0; j < 8; ++j) o[j] = (_Float16)(alpha * s[j] - beta * (float)xm2[j]);
  *(half8*)(Xout + i) = o;
}

// ---------------- Chebyshev conv2: fused full-K GEMM (R8, unchanged) ----------------
__global__ __launch_bounds__(256, 2) void k_cheb2(const _Float16* __restrict__ Xprev,
                                                  const _Float16* __restrict__ Lm,
                                                  const _Float16* __restrict__ Xm2,
                                                  _Float16* __restrict__ Xout,
                                                  float alpha, float beta) {
  __shared__ _Float16 lds[3][8192];  // [buf][A:64x64 (8KB) | B:64x64 (8KB)]
  const int t = threadIdx.x;
  const int lane = t & 63;
  const int ln = lane & 15;
  const int g = lane >> 4;
  const int g16 = g << 4;
  const int w = t >> 6;
  const int wm = w >> 1, wn = w & 1;
  const int bx = blockIdx.x & 15;
  const int by = blockIdx.x >> 4;
  const int v0 = bx * 64, m0 = by * 64;
  const size_t rs = 2048;  // 1024 * 2B

  const char* Ag = (const char*)Xprev + (size_t)m0 * rs;
  const char* Bg = (const char*)Lm + (size_t)v0 * rs;

  f32x4 acc[2][2] = {};

  auto stageHalf = [&](int buf, int tt, int half) {  // 2 gload_lds / thread
    const char* src = (half == 0) ? Ag : Bg;
    char* dst0 = (char*)&lds[buf][0] + half * 8192;
#pragma unroll
    for (int j = 0; j < 2; ++j) {
      const int idx = j * 256 + t;
      const int row = idx >> 3, c8 = idx & 7;
      gload_lds16(src + (size_t)row * rs + tt * 128 + ((c8 ^ (row & 7)) << 4),
                  dst0 + idx * 16);
    }
  };

  stageHalf(0, 0, 0); stageHalf(0, 0, 1);
  stageHalf(1, 1, 0); stageHalf(1, 1, 1);
  asm volatile("s_waitcnt vmcnt(4)" ::: "memory");
  asm volatile("s_barrier" ::: "memory");

  for (int tt = 0; tt < 16; ++tt) {
    const int cur = tt % 3;
    const int nxt = (tt + 2) % 3;
    const char* A = (const char*)&lds[cur][0];
    const char* B = A + 8192;
    half8 a[2][2], b[2][2];
#pragma unroll
    for (int kk = 0; kk < 2; ++kk) {
#pragma unroll
      for (int mi = 0; mi < 2; ++mi) {
        const int ar = wm * 32 + mi * 16 + ln;
        a[kk][mi] = *(const half8*)(A + ar * 128 + ((kk * 64 + g16) ^ ((ar & 7) << 4)));
      }
#pragma unroll
      for (int ni = 0; ni < 2; ++ni) {
        const int br = wn * 32 + ni * 16 + ln;
        b[kk][ni] = *(const half8*)(B + br * 128 + ((kk * 64 + g16) ^ ((br & 7) << 4)));
      }
    }
    if (tt + 2 < 16) {
      stageHalf(nxt, tt + 2, 0);
      stageHalf(nxt, tt + 2, 1);
      asm volatile("s_waitcnt vmcnt(4)" ::: "memory");
    } else {
      asm volatile("s_waitcnt vmcnt(0)" ::: "memory");
    }
    asm volatile("s_barrier" ::: "memory");
    asm volatile("s_waitcnt lgkmcnt(0)" ::: "memory");
    __builtin_amdgcn_sched_barrier(0);
    __builtin_amdgcn_s_setprio(1);
#pragma unroll
    for (int kk = 0; kk < 2; ++kk)
#pragma unroll
      for (int mi = 0; mi < 2; ++mi)
#pragma unroll
        for (int ni = 0; ni < 2; ++ni)
          acc[mi][ni] = __builtin_amdgcn_mfma_f32_16x16x32_f16(a[kk][mi], b[kk][ni],
                                                               acc[mi][ni], 0, 0, 0);
    __builtin_amdgcn_s_setprio(0);
    asm volatile("s_barrier" ::: "memory");
  }

#pragma unroll
  for (int mi = 0; mi < 2; ++mi) {
#pragma unroll
    for (int ni = 0; ni < 2; ++ni) {
      const int vv = v0 + wn * 32 + ni * 16 + ln;
      const int mmb = m0 + wm * 32 + mi * 16 + g * 4;
#pragma unroll
      for (int r = 0; r < 4; ++r) {
        const size_t idx = (size_t)(mmb + r) * 1024 + vv;
        float val = alpha * acc[mi][ni][r];
        if (beta != 0.f) val -= (float)Xm2[idx];
        Xout[idx] = (_Float16)val;
      }
    }
  }
}

// ---------------- Dense projection GEMM, gload_lds + counted vmcnt ----------------
template <int FT>
__global__ __launch_bounds__(256, 2) void k_dense(const _Float16* __restrict__ Wp,
                                                  const _Float16* __restrict__ XS,
                                                  const float* __restrict__ bias,
                                                  float* __restrict__ Yt,
                                                  int Vv, int shiftC, int nsteps,
                                                  int Ntot, float ascale, float bscale) {
  __shared__ _Float16 Alds[2][FT * 64];
  __shared__ _Float16 Blds[2][64 * 64];
  const int t = threadIdx.x;
  const int lane = t & 63;
  const int g = lane >> 4;
  const int w = t >> 6;
  const int n0 = blockIdx.x * 64;
  const int b = n0 / Vv;
  const int vb = n0 % Vv;
  const int Kp = nsteps * 64;
  const int cmask = (1 << shiftC) - 1;
  const size_t plane = 2097152;

  f32x4 acc[FT / 16] = {};

  auto stage = [&](int buf, int s) {
    const int q0 = s * 64;
    char* A = (char*)&Alds[buf][0];
    char* B = (char*)&Blds[buf][0];
#pragma unroll
    for (int j = 0; j < FT / 32; ++j) {
      const int ch = j * 256 + t;
      const int f = ch >> 3, c8 = ch & 7;
      gload_lds16((const char*)Wp + ((size_t)f * Kp + q0) * 2 + ((c8 ^ (f & 7)) << 4),
                  A + ch * 16);
    }
#pragma unroll
    for (int j = 0; j < 2; ++j) {
      const int ch = j * 256 + t;
      const int q = ch >> 3, c8 = ch & 7;
      const int qq = q0 + q;
      const int k = qq >> shiftC, c = qq & cmask;
      const int sz = (q >> 3) & 7;
      gload_lds16((const char*)XS + ((size_t)k * plane + (size_t)(c * 32 + b) * Vv + vb) * 2 +
                      ((c8 ^ sz) << 4),
                  B + ch * 16);
    }
  };

  stage(0, 0);

  for (int s = 0; s < nsteps; ++s) {
    const int cur = s & 1;
    if (s + 1 < nsteps) {
      stage(cur ^ 1, s + 1);
      if constexpr (FT == 64) {
        asm volatile("s_waitcnt vmcnt(4)" ::: "memory");
      } else {
        asm volatile("s_waitcnt vmcnt(6)" ::: "memory");
      }
    } else {
      asm volatile("s_waitcnt vmcnt(0)" ::: "memory");
    }
    asm volatile("s_barrier" ::: "memory");
    const _Float16* A = &Alds[cur][0];
    const _Float16* B = &Blds[cur][0];
#pragma unroll
    for (int kk = 0; kk < 2; ++kk) {
      half8 bf;
      const int c = lane & 15;
#pragma unroll
      for (int j = 0; j < 8; ++j) {
        const int q = kk * 32 + g * 8 + j;
        const int sz = (q >> 3) & 7;
        bf[j] = B[q * 64 + ((w * 16 + c) ^ (sz << 3))];
      }
#pragma unroll
      for (int mi = 0; mi < FT / 16; ++mi) {
        const int ar = mi * 16 + c;
        half8 af = *(const half8*)((const char*)A + ar * 128 +
                                   ((kk * 64 + g * 16) ^ ((ar & 7) << 4)));
        acc[mi] = __builtin_amdgcn_mfma_f32_16x16x32_f16(af, bf, acc[mi], 0, 0, 0);
      }
    }
    asm volatile("s_barrier" ::: "memory");
  }

  const int n = n0 + w * 16 + (lane & 15);
#pragma unroll
  for (int mi = 0; mi < FT / 16; ++mi) {
#pragma unroll
    for (int r = 0; r < 4; ++r) {
      const int f = mi * 16 + g * 4 + r;
      Yt[(size_t)f * Ntot + n] = fmaxf(ascale * acc[mi][r] + bscale * bias[f], 0.f);
    }
  }
}

// ---------------- pool1 ----------------
__global__ __launch_bounds__(256) void k_pool1(const float* __restrict__ Yt,
                                               _Float16* __restrict__ X2) {
  const int idx = blockIdx.x * 256 + threadIdx.x;
  const int v2 = idx & 1023;
  const int rest = idx >> 10;
  const int b = rest & 31;
  const int f = rest >> 5;
  f32x4 q = *(const f32x4*)(Yt + (size_t)f * 131072 + b * 4096 + v2 * 4);
  float mx = fmaxf(fmaxf(q[0], q[1]), fmaxf(q[2], q[3]));
  X2[(size_t)(f * 32 + b) * 1024 + v2] = (_Float16)(mx * 0.015625f);
}

// ---------------- pool2 ----------------
__global__ __launch_bounds__(256) void k_pool2(const float* __restrict__ Yt,
                                               float* __restrict__ p2) {
  const int idx = blockIdx.x * 256 + threadIdx.x;
  const int v3 = idx & 255;
  const int rest = idx >> 8;
  const int f = rest & 127;
  const int b = rest >> 7;
  f32x4 q = *(const f32x4*)(Yt + (size_t)f * 32768 + b * 1024 + v3 * 4);
  float mx = fmaxf(fmaxf(q[0], q[1]), fmaxf(q[2], q[3]));
  p2[(size_t)b * 32768 + f * 256 + v3] = mx;
}

// ---------------- FC pass 1 ----------------
__global__ __launch_bounds__(256) void k_fc_part(const float* __restrict__ p2,
                                                 const float* __restrict__ Wfc,
                                                 float* __restrict__ partF) {
  const int b = blockIdx.x >> 3;
  const int seg = blockIdx.x & 7;
  const int t = threadIdx.x;
  const int lane = t & 63;
  const int w = t >> 6;
  const int base = seg * 4096;
  float acc[10];
#pragma unroll
  for (int o = 0; o < 10; ++o) acc[o] = 0.f;
  const float* pb = p2 + (size_t)b * 32768 + base;
  for (int i = t; i < 4096; i += 256) {
    float p = pb[i];
#pragma unroll
    for (int o = 0; o < 10; ++o) acc[o] += p * Wfc[(size_t)o * 32768 + base + i];
  }
#pragma unroll
  for (int off = 32; off > 0; off >>= 1)
#pragma unroll
    for (int o = 0; o < 10; ++o) acc[o] += __shfl_down(acc[o], off);
  __shared__ float rws[10][4];
  if (lane == 0) {
#pragma unroll
    for (int o = 0; o < 10; ++o) rws[o][w] = acc[o];
  }
  __syncthreads();
  if (t < 10) partF[blockIdx.x * 10 + t] =
      rws[t][0] + rws[t][1] + rws[t][2] + rws[t][3];
}

// ---------------- FC pass 2 ----------------
__global__ void k_fc_final(const float* __restrict__ partF,
                           const float* __restrict__ bfc,
                           float* __restrict__ out) {
  const int t = threadIdx.x;
  if (t < 320) {
    const int b = t / 10, o = t - b * 10;
    float s = 0.f;
#pragma unroll
    for (int seg = 0; seg < 8; ++seg) s += partF[(b * 8 + seg) * 10 + o];
    out[b * 10 + o] = 64.f * s + bfc[o];
  }
}

extern "C" void kernel_launch(void* const* d_in, const int* in_sizes, int n_in,
                              void* d_out, int out_size, void* d_ws, size_t ws_size,
                              hipStream_t stream) {
  (void)in_sizes; (void)n_in; (void)out_size; (void)ws_size;
  const float* x = (const float*)d_in[0];
  const int* perm = (const int*)d_in[1];
  const float* L1 = (const float*)d_in[2];
  const float* L2 = (const float*)d_in[3];
  const float* W1 = (const float*)d_in[4];
  const float* b1 = (const float*)d_in[5];
  const float* W2 = (const float*)d_in[6];
  const float* b2 = (const float*)d_in[7];
  const float* Wfc = (const float*)d_in[8];
  const float* bfc = (const float*)d_in[9];
  float* out = (float*)d_out;

  char* ws = (char*)d_ws;
  size_t off = 0;
  auto alloc = [&](size_t bytes) {
    char* p = ws + off;
    off += (bytes + 255) & ~(size_t)255;
    return p;
  };
  _Float16* L1h = (_Float16*)alloc(16777216ull * 2);
  _Float16* L2h = (_Float16*)alloc(1048576ull * 2);
  _Float16* W1p = (_Float16*)alloc(64ull * 448 * 2);
  _Float16* W2p = (_Float16*)alloc(128ull * 1664 * 2);
  float* part = (float*)alloc(256 * 4);
  float* musig = (float*)alloc(32 * 4);
  float* partF = (float*)alloc(2560 * 4);
  _Float16* XS = (_Float16*)alloc(28ull * 2097152 * 2);   // 25 states + 3 zero planes
  float* Yt = (float*)alloc(64ull * 131072 * 4);          // 32MB; aliased as Pq during conv1
  float* p2 = (float*)alloc(32ull * 128 * 256 * 4);
  _Float16* Pq = (_Float16*)Yt;  // 8 partial planes (32MB), dead before dense1 writes Yt

  const size_t plane = 2097152;

  k_cvt_f16<<<16384, 256, 0, stream>>>(L1, L1h, 16777216);
  k_cvt_f16<<<1024, 256, 0, stream>>>(L2, L2h, 1048576);
  k_prep_w<<<112, 256, 0, stream>>>(W1, W1p, 64, 4, 28);
  k_prep_w<<<832, 256, 0, stream>>>(W2, W2p, 128, 6, 26);
  k_zero<<<3072, 256, 0, stream>>>(XS + 25 * plane, 786432);
  k_bn_partial<<<128, 256, 0, stream>>>(x, part);
  k_bn_final<<<1, 64, 0, stream>>>(part, musig);
  k_build_x0<<<8192, 256, 0, stream>>>(x, perm, musig, XS);

  // conv1: grid 256 = kq8 (fastest, XCD-resident) x bx16 x by2, K-slice 512
  for (int k = 1; k < 25; ++k) {
    k_cheb1<<<256, 512, 0, stream>>>(XS + (size_t)(k - 1) * plane, L1h, Pq);
    k_cheb_red8<<<1024, 256, 0, stream>>>(
        Pq, XS + (size_t)(k >= 2 ? k - 2 : 0) * plane, XS + (size_t)k * plane,
        (k == 1) ? 1.f : 2.f, (k == 1) ? 0.f : 1.f);
  }
  k_dense<64><<<dim3(2048, 1), 256, 0, stream>>>(W1p, XS, b1, Yt, 4096, 4, 7,
                                                 131072, 16.f, 1.f);
  k_pool1<<<8192, 256, 0, stream>>>(Yt, XS);
  // conv2: fused full-K kernel, grid 512 = by32 x bx16, 2 blocks/CU
  for (int k = 1; k < 25; ++k) {
    k_cheb2<<<512, 256, 0, stream>>>(
        XS + (size_t)(k - 1) * plane, L2h,
        XS + (size_t)(k >= 2 ? k - 2 : 0) * plane, XS + (size_t)k * plane,
        (k == 1) ? 1.f : 2.f, (k == 1) ? 0.f : 1.f);
  }
  k_dense<128><<<dim3(512, 1), 256, 0, stream>>>(W2p, XS, b2, Yt, 1024, 6, 26,
                                                 32768, 1.f, 0.015625f);
  k_pool2<<<4096, 256, 0, stream>>>(Yt, p2);
  k_fc_part<<<256, 256, 0, stream>>>(p2, Wfc, partF);
  k_fc_final<<<1, 320, 0, stream>>>(partF, bfc, out);
}

// Round 13
// 1188.035 us; speedup vs baseline: 1.0301x; 1.0291x over previous
//
#include <hip/hip_runtime.h>

typedef _Float16 half8 __attribute__((ext_vector_type(8)));
typedef _Float16 half4 __attribute__((ext_vector_type(4)));
typedef float f32x4 __attribute__((ext_vector_type(4)));

__device__ __forceinline__ void gload_lds16(const void* g, void* l) {
  __builtin_amdgcn_global_load_lds((const __attribute__((address_space(1))) void*)g,
                                   (__attribute__((address_space(3))) void*)l, 16, 0, 0);
}

// ---------------- BN partial sums: grid 128 = (seg<<4 | c) ----------------
__global__ __launch_bounds__(256) void k_bn_partial(const float* __restrict__ x,
                                                    float* __restrict__ part) {
  const int c = blockIdx.x & 15;
  const int seg = blockIdx.x >> 4;
  const int t = threadIdx.x;
  float s = 0.f, s2 = 0.f;
  for (int b = 0; b < 32; ++b) {
    const float* row = x + (size_t)(b * 16 + c) * 4000 + seg * 500;
    for (int v = t; v < 500; v += 256) {
      float val = row[v];
      s += val;
      s2 += val * val;
    }
  }
#pragma unroll
  for (int off = 32; off > 0; off >>= 1) {
    s += __shfl_down(s, off);
    s2 += __shfl_down(s2, off);
  }
  __shared__ float rs_[4], rs2_[4];
  if ((t & 63) == 0) { rs_[t >> 6] = s; rs2_[t >> 6] = s2; }
  __syncthreads();
  if (t == 0) {
    part[c * 8 + seg] = rs_[0] + rs_[1] + rs_[2] + rs_[3];
    part[128 + c * 8 + seg] = rs2_[0] + rs2_[1] + rs2_[2] + rs2_[3];
  }
}

// ---------------- BN finalize ----------------
__global__ void k_bn_final(const float* __restrict__ part, float* __restrict__ musig) {
  const int c = threadIdx.x;
  if (c < 16) {
    float S = 0.f, S2 = 0.f;
#pragma unroll
    for (int seg = 0; seg < 8; ++seg) {
      S += part[c * 8 + seg];
      S2 += part[128 + c * 8 + seg];
    }
    const float inv = 1.f / 128000.f;
    float mu = S * inv;
    float var = S2 * inv - mu * mu;
    musig[c] = mu;
    musig[16 + c] = rsqrtf(var + 1e-5f);
  }
}

// ---------------- build x0 (normalized, permuted, transposed, scaled 1/16) ----------------
__global__ __launch_bounds__(256) void k_build_x0(const float* __restrict__ x,
                                                  const int* __restrict__ perm,
                                                  const float* __restrict__ musig,
                                                  _Float16* __restrict__ X0) {
  const int idx = blockIdx.x * 256 + threadIdx.x;
  const int v = idx & 4095;
  const int m = idx >> 12;
  const int b = m & 31;
  const int c = m >> 5;
  const int pv = perm[v];
  float val = 0.f;
  if (pv < 4000)
    val = (x[((size_t)(b * 16 + c)) * 4000 + pv] - musig[c]) * musig[16 + c] * 0.0625f;
  X0[idx] = (_Float16)val;
}

// ---------------- f32 -> f16 convert ----------------
__global__ __launch_bounds__(256) void k_cvt_f16(const float* __restrict__ s,
                                                 _Float16* __restrict__ d, int n) {
  const int i = (blockIdx.x * 256 + threadIdx.x) * 4;
  if (i >= n) return;
  f32x4 v = *(const f32x4*)(s + i);
  half4 h;
  h[0] = (_Float16)v[0]; h[1] = (_Float16)v[1];
  h[2] = (_Float16)v[2]; h[3] = (_Float16)v[3];
  *(half4*)(d + i) = h;
}

// ---------------- zero fill ----------------
__global__ __launch_bounds__(256) void k_zero(_Float16* __restrict__ p, int n8) {
  const int i = blockIdx.x * 256 + threadIdx.x;
  if (i < n8) *(half8*)(p + (size_t)i * 8) = half8{};
}

// ---------------- W permute+pad: Wp[f][k*CS + c] = W[f][c*25 + k] ----------------
__global__ __launch_bounds__(256) void k_prep_w(const float* __restrict__ W,
                                                _Float16* __restrict__ Wp,
                                                int F, int shiftC, int kround) {
  const int idx = blockIdx.x * 256 + threadIdx.x;
  const int CS = 1 << shiftC;
  const int KPtot = kround * CS;
  if (idx >= F * KPtot) return;
  const int f = idx / KPtot;
  const int rem = idx - f * KPtot;
  const int k = rem >> shiftC;
  const int c = rem & (CS - 1);
  float v = 0.f;
  if (k < 25) v = W[(size_t)f * (CS * 25) + c * 25 + k];
  Wp[idx] = (_Float16)v;
}

// ---------------- Chebyshev conv1 partial GEMM: 128x128 tile, BK=32, 2 blocks/CU ----------------
// P[kq][m][v] = sum_{u in kq K-slice(1024)} Xprev[m][u] * L[v][u]
// Grid 512 = kq4 (bid&3) x bx32 x by4 -> 2 blocks/CU (the occupancy lever:
// every 1-blk/CU conv1 variant pinned at ~23us regardless of schedule/traffic).
// 256 thr = 4 waves (2m x 2v), wave 64x64 (4x4 frags). 3-buf LDS 48KB.
// NT=32 deep pipeline, 2-ahead staging (4 gload/thread/tile), counted vmcnt(4).
// 64B-row swizzle slot c8 ^ ((row>>1)&3) (R9/R12-verified: correct, 2-way banks).
__global__ __launch_bounds__(256, 2) void k_cheb1b(const _Float16* __restrict__ Xprev,
                                                   const _Float16* __restrict__ Lm,
                                                   _Float16* __restrict__ P) {
  __shared__ _Float16 lds[3][8192];  // [buf][A:128x32 (8KB) | B:128x32 (8KB)]
  const int t = threadIdx.x;
  const int lane = t & 63;
  const int ln = lane & 15;
  const int g = lane >> 4;
  const int w = t >> 6;
  const int wm = w >> 1, wn = w & 1;
  const int bid = blockIdx.x;
  const int kq = bid & 3;
  const int bx = (bid >> 2) & 31;
  const int by = bid >> 7;
  const int v0 = bx * 128, m0 = by * 128;
  const size_t rs = 8192;  // 4096 * 2B

  const char* Ag = (const char*)Xprev + (size_t)m0 * rs + kq * 2048;
  const char* Bg = (const char*)Lm + (size_t)v0 * rs + kq * 2048;

  f32x4 acc[4][4] = {};

  auto stage = [&](int buf, int tt) {  // 4 gload_lds / thread
    char* A = (char*)&lds[buf][0];
    char* B = (char*)&lds[buf][4096];
#pragma unroll
    for (int j = 0; j < 2; ++j) {
      const int ch = j * 256 + t;          // 0..511 chunks (128 rows x 4 slots)
      const int row = ch >> 2, c8 = ch & 3;
      const size_t so = (size_t)row * rs + tt * 64 + ((c8 ^ ((row >> 1) & 3)) << 4);
      gload_lds16(Ag + so, A + ch * 16);
      gload_lds16(Bg + so, B + ch * 16);
    }
  };

  // prologue: T0, T1 staged; vmcnt(4) = own T0 landed (T1's 4 in flight)
  stage(0, 0);
  stage(1, 1);
  asm volatile("s_waitcnt vmcnt(4)" ::: "memory");
  asm volatile("s_barrier" ::: "memory");

  for (int tt = 0; tt < 32; ++tt) {
    const int cur = tt % 3;
    const char* A = (const char*)&lds[cur][0];
    const char* B = A + 8192;
    half8 a[4], b[4];
#pragma unroll
    for (int mi = 0; mi < 4; ++mi) {
      const int ar = wm * 64 + mi * 16 + ln;
      a[mi] = *(const half8*)(A + ar * 64 + ((g ^ ((ar >> 1) & 3)) << 4));
    }
#pragma unroll
    for (int ni = 0; ni < 4; ++ni) {
      const int br = wn * 64 + ni * 16 + ln;
      b[ni] = *(const half8*)(B + br * 64 + ((g ^ ((br >> 1) & 3)) << 4));
    }
    if (tt + 2 < 32) {
      stage((tt + 2) % 3, tt + 2);
      asm volatile("s_waitcnt vmcnt(4)" ::: "memory");  // T+1 landed, T+2 in flight
    } else {
      asm volatile("s_waitcnt vmcnt(0)" ::: "memory");  // tail drain
    }
    asm volatile("s_barrier" ::: "memory");
    asm volatile("s_waitcnt lgkmcnt(0)" ::: "memory");
    __builtin_amdgcn_sched_barrier(0);
    __builtin_amdgcn_s_setprio(1);
#pragma unroll
    for (int mi = 0; mi < 4; ++mi)
#pragma unroll
      for (int ni = 0; ni < 4; ++ni)
        acc[mi][ni] = __builtin_amdgcn_mfma_f32_16x16x32_f16(a[mi], b[ni], acc[mi][ni], 0, 0, 0);
    __builtin_amdgcn_s_setprio(0);
    asm volatile("s_barrier" ::: "memory");
  }

  // epilogue: write fp16 partial plane kq
  _Float16* Pq = P + (size_t)kq * 2097152;
#pragma unroll
  for (int mi = 0; mi < 4; ++mi) {
#pragma unroll
    for (int ni = 0; ni < 4; ++ni) {
      const int vv = v0 + wn * 64 + ni * 16 + ln;
      const int mmb = m0 + wm * 64 + mi * 16 + g * 4;
#pragma unroll
      for (int r = 0; r < 4; ++r)
        Pq[(size_t)(mmb + r) * 4096 + vv] = (_Float16)acc[mi][ni][r];
    }
  }
}

// ---------------- reduce 4 partials: Xout = alpha*(P0+..+P3) - beta*Xm2 ----------------
__global__ __launch_bounds__(256) void k_cheb_red4(const _Float16* __restrict__ P,
                                                   const _Float16* __restrict__ Xm2,
                                                   _Float16* __restrict__ Xout,
                                                   float alpha, float beta) {
  const size_t i = ((size_t)blockIdx.x * 256 + threadIdx.x) * 8;
  float s[8] = {};
#pragma unroll
  for (int p = 0; p < 4; ++p) {
    half8 v = *(const half8*)(P + (size_t)p * 2097152 + i);
#pragma unroll
    for (int j = 0; j < 8; ++j) s[j] += (float)v[j];
  }
  half8 xm2 = {};
  if (beta != 0.f) xm2 = *(const half8*)(Xm2 + i);
  half8 o;
#pragma unroll
  for (int j = 0; j < 8; ++j) o[j] = (_Float16)(alpha * s[j] - beta * (float)xm2[j]);
  *(half8*)(Xout + i) = o;
}

// ---------------- Chebyshev conv2: fused full-K GEMM (R8, unchanged) ----------------
__global__ __launch_bounds__(256, 2) void k_cheb2(const _Float16* __restrict__ Xprev,
                                                  const _Float16* __restrict__ Lm,
                                                  const _Float16* __restrict__ Xm2,
                                                  _Float16* __restrict__ Xout,
                                                  float alpha, float beta) {
  __shared__ _Float16 lds[3][8192];  // [buf][A:64x64 (8KB) | B:64x64 (8KB)]
  const int t = threadIdx.x;
  const int lane = t & 63;
  const int ln = lane & 15;
  const int g = lane >> 4;
  const int g16 = g << 4;
  const int w = t >> 6;
  const int wm = w >> 1, wn = w & 1;
  const int bx = blockIdx.x & 15;
  const int by = blockIdx.x >> 4;
  const int v0 = bx * 64, m0 = by * 64;
  const size_t rs = 2048;  // 1024 * 2B

  const char* Ag = (const char*)Xprev + (size_t)m0 * rs;
  const char* Bg = (const char*)Lm + (size_t)v0 * rs;

  f32x4 acc[2][2] = {};

  auto stageHalf = [&](int buf, int tt, int half) {  // 2 gload_lds / thread
    const char* src = (half == 0) ? Ag : Bg;
    char* dst0 = (char*)&lds[buf][0] + half * 8192;
#pragma unroll
    for (int j = 0; j < 2; ++j) {
      const int idx = j * 256 + t;
      const int row = idx >> 3, c8 = idx & 7;
      gload_lds16(src + (size_t)row * rs + tt * 128 + ((c8 ^ (row & 7)) << 4),
                  dst0 + idx * 16);
    }
  };

  stageHalf(0, 0, 0); stageHalf(0, 0, 1);
  stageHalf(1, 1, 0); stageHalf(1, 1, 1);
  asm volatile("s_waitcnt vmcnt(4)" ::: "memory");
  asm volatile("s_barrier" ::: "memory");

  for (int tt = 0; tt < 16; ++tt) {
    const int cur = tt % 3;
    const int nxt = (tt + 2) % 3;
    const char* A = (const char*)&lds[cur][0];
    const char* B = A + 8192;
    half8 a[2][2], b[2][2];
#pragma unroll
    for (int kk = 0; kk < 2; ++kk) {
#pragma unroll
      for (int mi = 0; mi < 2; ++mi) {
        const int ar = wm * 32 + mi * 16 + ln;
        a[kk][mi] = *(const half8*)(A + ar * 128 + ((kk * 64 + g16) ^ ((ar & 7) << 4)));
      }
#pragma unroll
      for (int ni = 0; ni < 2; ++ni) {
        const int br = wn * 32 + ni * 16 + ln;
        b[kk][ni] = *(const half8*)(B + br * 128 + ((kk * 64 + g16) ^ ((br & 7) << 4)));
      }
    }
    if (tt + 2 < 16) {
      stageHalf(nxt, tt + 2, 0);
      stageHalf(nxt, tt + 2, 1);
      asm volatile("s_waitcnt vmcnt(4)" ::: "memory");
    } else {
      asm volatile("s_waitcnt vmcnt(0)" ::: "memory");
    }
    asm volatile("s_barrier" ::: "memory");
    asm volatile("s_waitcnt lgkmcnt(0)" ::: "memory");
    __builtin_amdgcn_sched_barrier(0);
    __builtin_amdgcn_s_setprio(1);
#pragma unroll
    for (int kk = 0; kk < 2; ++kk)
#pragma unroll
      for (int mi = 0; mi < 2; ++mi)
#pragma unroll
        for (int ni = 0; ni < 2; ++ni)
          acc[mi][ni] = __builtin_amdgcn_mfma_f32_16x16x32_f16(a[kk][mi], b[kk][ni],
                                                               acc[mi][ni], 0, 0, 0);
    __builtin_amdgcn_s_setprio(0);
    asm volatile("s_barrier" ::: "memory");
  }

#pragma unroll
  for (int mi = 0; mi < 2; ++mi) {
#pragma unroll
    for (int ni = 0; ni < 2; ++ni) {
      const int vv = v0 + wn * 32 + ni * 16 + ln;
      const int mmb = m0 + wm * 32 + mi * 16 + g * 4;
#pragma unroll
      for (int r = 0; r < 4; ++r) {
        const size_t idx = (size_t)(mmb + r) * 1024 + vv;
        float val = alpha * acc[mi][ni][r];
        if (beta != 0.f) val -= (float)Xm2[idx];
        Xout[idx] = (_Float16)val;
      }
    }
  }
}

// ---------------- Dense projection GEMM, gload_lds + counted vmcnt ----------------
template <int FT>
__global__ __launch_bounds__(256, 2) void k_dense(const _Float16* __restrict__ Wp,
                                                  const _Float16* __restrict__ XS,
                                                  const float* __restrict__ bias,
                                                  float* __restrict__ Yt,
                                                  int Vv, int shiftC, int nsteps,
                                                  int Ntot, float ascale, float bscale) {
  __shared__ _Float16 Alds[2][FT * 64];
  __shared__ _Float16 Blds[2][64 * 64];
  const int t = threadIdx.x;
  const int lane = t & 63;
  const int g = lane >> 4;
  const int w = t >> 6;
  const int n0 = blockIdx.x * 64;
  const int b = n0 / Vv;
  const int vb = n0 % Vv;
  const int Kp = nsteps * 64;
  const int cmask = (1 << shiftC) - 1;
  const size_t plane = 2097152;

  f32x4 acc[FT / 16] = {};

  auto stage = [&](int buf, int s) {
    const int q0 = s * 64;
    char* A = (char*)&Alds[buf][0];
    char* B = (char*)&Blds[buf][0];
#pragma unroll
    for (int j = 0; j < FT / 32; ++j) {
      const int ch = j * 256 + t;
      const int f = ch >> 3, c8 = ch & 7;
      gload_lds16((const char*)Wp + ((size_t)f * Kp + q0) * 2 + ((c8 ^ (f & 7)) << 4),
                  A + ch * 16);
    }
#pragma unroll
    for (int j = 0; j < 2; ++j) {
      const int ch = j * 256 + t;
      const int q = ch >> 3, c8 = ch & 7;
      const int qq = q0 + q;
      const int k = qq >> shiftC, c = qq & cmask;
      const int sz = (q >> 3) & 7;
      gload_lds16((const char*)XS + ((size_t)k * plane + (size_t)(c * 32 + b) * Vv + vb) * 2 +
                      ((c8 ^ sz) << 4),
                  B + ch * 16);
    }
  };

  stage(0, 0);

  for (int s = 0; s < nsteps; ++s) {
    const int cur = s & 1;
    if (s + 1 < nsteps) {
      stage(cur ^ 1, s + 1);
      if constexpr (FT == 64) {
        asm volatile("s_waitcnt vmcnt(4)" ::: "memory");
      } else {
        asm volatile("s_waitcnt vmcnt(6)" ::: "memory");
      }
    } else {
      asm volatile("s_waitcnt vmcnt(0)" ::: "memory");
    }
    asm volatile("s_barrier" ::: "memory");
    const _Float16* A = &Alds[cur][0];
    const _Float16* B = &Blds[cur][0];
#pragma unroll
    for (int kk = 0; kk < 2; ++kk) {
      half8 bf;
      const int c = lane & 15;
#pragma unroll
      for (int j = 0; j < 8; ++j) {
        const int q = kk * 32 + g * 8 + j;
        const int sz = (q >> 3) & 7;
        bf[j] = B[q * 64 + ((w * 16 + c) ^ (sz << 3))];
      }
#pragma unroll
      for (int mi = 0; mi < FT / 16; ++mi) {
        const int ar = mi * 16 + c;
        half8 af = *(const half8*)((const char*)A + ar * 128 +
                                   ((kk * 64 + g * 16) ^ ((ar & 7) << 4)));
        acc[mi] = __builtin_amdgcn_mfma_f32_16x16x32_f16(af, bf, acc[mi], 0, 0, 0);
      }
    }
    asm volatile("s_barrier" ::: "memory");
  }

  const int n = n0 + w * 16 + (lane & 15);
#pragma unroll
  for (int mi = 0; mi < FT / 16; ++mi) {
#pragma unroll
    for (int r = 0; r < 4; ++r) {
      const int f = mi * 16 + g * 4 + r;
      Yt[(size_t)f * Ntot + n] = fmaxf(ascale * acc[mi][r] + bscale * bias[f], 0.f);
    }
  }
}

// ---------------- pool1 ----------------
__global__ __launch_bounds__(256) void k_pool1(const float* __restrict__ Yt,
                                               _Float16* __restrict__ X2) {
  const int idx = blockIdx.x * 256 + threadIdx.x;
  const int v2 = idx & 1023;
  const int rest = idx >> 10;
  const int b = rest & 31;
  const int f = rest >> 5;
  f32x4 q = *(const f32x4*)(Yt + (size_t)f * 131072 + b * 4096 + v2 * 4);
  float mx = fmaxf(fmaxf(q[0], q[1]), fmaxf(q[2], q[3]));
  X2[(size_t)(f * 32 + b) * 1024 + v2] = (_Float16)(mx * 0.015625f);
}

// ---------------- pool2 ----------------
__global__ __launch_bounds__(256) void k_pool2(const float* __restrict__ Yt,
                                               float* __restrict__ p2) {
  const int idx = blockIdx.x * 256 + threadIdx.x;
  const int v3 = idx & 255;
  const int rest = idx >> 8;
  const int f = rest & 127;
  const int b = rest >> 7;
  f32x4 q = *(const f32x4*)(Yt + (size_t)f * 32768 + b * 1024 + v3 * 4);
  float mx = fmaxf(fmaxf(q[0], q[1]), fmaxf(q[2], q[3]));
  p2[(size_t)b * 32768 + f * 256 + v3] = mx;
}

// ---------------- FC pass 1 ----------------
__global__ __launch_bounds__(256) void k_fc_part(const float* __restrict__ p2,
                                                 const float* __restrict__ Wfc,
                                                 float* __restrict__ partF) {
  const int b = blockIdx.x >> 3;
  const int seg = blockIdx.x & 7;
  const int t = threadIdx.x;
  const int lane = t & 63;
  const int w = t >> 6;
  const int base = seg * 4096;
  float acc[10];
#pragma unroll
  for (int o = 0; o < 10; ++o) acc[o] = 0.f;
  const float* pb = p2 + (size_t)b * 32768 + base;
  for (int i = t; i < 4096; i += 256) {
    float p = pb[i];
#pragma unroll
    for (int o = 0; o < 10; ++o) acc[o] += p * Wfc[(size_t)o * 32768 + base + i];
  }
#pragma unroll
  for (int off = 32; off > 0; off >>= 1)
#pragma unroll
    for (int o = 0; o < 10; ++o) acc[o] += __shfl_down(acc[o], off);
  __shared__ float rws[10][4];
  if (lane == 0) {
#pragma unroll
    for (int o = 0; o < 10; ++o) rws[o][w] = acc[o];
  }
  __syncthreads();
  if (t < 10) partF[blockIdx.x * 10 + t] =
      rws[t][0] + rws[t][1] + rws[t][2] + rws[t][3];
}

// ---------------- FC pass 2 ----------------
__global__ void k_fc_final(const float* __restrict__ partF,
                           const float* __restrict__ bfc,
                           float* __restrict__ out) {
  const int t = threadIdx.x;
  if (t < 320) {
    const int b = t / 10, o = t - b * 10;
    float s = 0.f;
#pragma unroll
    for (int seg = 0; seg < 8; ++seg) s += partF[(b * 8 + seg) * 10 + o];
    out[b * 10 + o] = 64.f * s + bfc[o];
  }
}

extern "C" void kernel_launch(void* const* d_in, const int* in_sizes, int n_in,
                              void* d_out, int out_size, void* d_ws, size_t ws_size,
                              hipStream_t stream) {
  (void)in_sizes; (void)n_in; (void)out_size; (void)ws_size;
  const float* x = (const float*)d_in[0];
  const int* perm = (const int*)d_in[1];
  const float* L1 = (const float*)d_in[2];
  const float* L2 = (const float*)d_in[3];
  const float* W1 = (const float*)d_in[4];
  const float* b1 = (const float*)d_in[5];
  const float* W2 = (const float*)d_in[6];
  const float* b2 = (const float*)d_in[7];
  const float* Wfc = (const float*)d_in[8];
  const float* bfc = (const float*)d_in[9];
  float* out = (float*)d_out;

  char* ws = (char*)d_ws;
  size_t off = 0;
  auto alloc = [&](size_t bytes) {
    char* p = ws + off;
    off += (bytes + 255) & ~(size_t)255;
    return p;
  };
  _Float16* L1h = (_Float16*)alloc(16777216ull * 2);
  _Float16* L2h = (_Float16*)alloc(1048576ull * 2);
  _Float16* W1p = (_Float16*)alloc(64ull * 448 * 2);
  _Float16* W2p = (_Float16*)alloc(128ull * 1664 * 2);
  float* part = (float*)alloc(256 * 4);
  float* musig = (float*)alloc(32 * 4);
  float* partF = (float*)alloc(2560 * 4);
  _Float16* XS = (_Float16*)alloc(28ull * 2097152 * 2);   // 25 states + 3 zero planes
  float* Yt = (float*)alloc(64ull * 131072 * 4);          // 32MB; aliased as Pq during conv1
  float* p2 = (float*)alloc(32ull * 128 * 256 * 4);
  _Float16* Pq = (_Float16*)Yt;  // 4 partial planes (16MB), dead before dense1 writes Yt

  const size_t plane = 2097152;

  k_cvt_f16<<<16384, 256, 0, stream>>>(L1, L1h, 16777216);
  k_cvt_f16<<<1024, 256, 0, stream>>>(L2, L2h, 1048576);
  k_prep_w<<<112, 256, 0, stream>>>(W1, W1p, 64, 4, 28);
  k_prep_w<<<832, 256, 0, stream>>>(W2, W2p, 128, 6, 26);
  k_zero<<<3072, 256, 0, stream>>>(XS + 25 * plane, 786432);
  k_bn_partial<<<128, 256, 0, stream>>>(x, part);
  k_bn_final<<<1, 64, 0, stream>>>(part, musig);
  k_build_x0<<<8192, 256, 0, stream>>>(x, perm, musig, XS);

  // conv1: grid 512 = kq4 (bid&3) x bx32 x by4 -> 2 blocks/CU, K-slice 1024
  for (int k = 1; k < 25; ++k) {
    k_cheb1b<<<512, 256, 0, stream>>>(XS + (size_t)(k - 1) * plane, L1h, Pq);
    k_cheb_red4<<<1024, 256, 0, stream>>>(
        Pq, XS + (size_t)(k >= 2 ? k - 2 : 0) * plane, XS + (size_t)k * plane,
        (k == 1) ? 1.f : 2.f, (k == 1) ? 0.f : 1.f);
  }
  k_dense<64><<<dim3(2048, 1), 256, 0, stream>>>(W1p, XS, b1, Yt, 4096, 4, 7,
                                                 131072, 16.f, 1.f);
  k_pool1<<<8192, 256, 0, stream>>>(Yt, XS);
  // conv2: fused full-K kernel, grid 512 = by32 x bx16, 2 blocks/CU
  for (int k = 1; k < 25; ++k) {
    k_cheb2<<<512, 256, 0, stream>>>(
        XS + (size_t)(k - 1) * plane, L2h,
        XS + (size_t)(k >= 2 ? k - 2 : 0) * plane, XS + (size_t)k * plane,
        (k == 1) ? 1.f : 2.f, (k == 1) ? 0.f : 1.f);
  }
  k_dense<128><<<dim3(512, 1), 256, 0, stream>>>(W2p, XS, b2, Yt, 1024, 6, 26,
                                                 32768, 1.f, 0.015625f);
  k_pool2<<<4096, 256, 0, stream>>>(Yt, p2);
  k_fc_part<<<256, 256, 0, stream>>>(p2, Wfc, partF);
  k_fc_final<<<1, 320, 0, stream>>>(partF, bfc, out);
}

// Round 14
// 1169.371 us; speedup vs baseline: 1.0466x; 1.0160x over previous
//
#include <hip/hip_runtime.h>

typedef _Float16 half8 __attribute__((ext_vector_type(8)));
typedef _Float16 half4 __attribute__((ext_vector_type(4)));
typedef float f32x4 __attribute__((ext_vector_type(4)));

__device__ __forceinline__ void gload_lds16(const void* g, void* l) {
  __builtin_amdgcn_global_load_lds((const __attribute__((address_space(1))) void*)g,
                                   (__attribute__((address_space(3))) void*)l, 16, 0, 0);
}

// ---------------- BN partial sums: grid 128 = (seg<<4 | c) ----------------
__global__ __launch_bounds__(256) void k_bn_partial(const float* __restrict__ x,
                                                    float* __restrict__ part) {
  const int c = blockIdx.x & 15;
  const int seg = blockIdx.x >> 4;
  const int t = threadIdx.x;
  float s = 0.f, s2 = 0.f;
  for (int b = 0; b < 32; ++b) {
    const float* row = x + (size_t)(b * 16 + c) * 4000 + seg * 500;
    for (int v = t; v < 500; v += 256) {
      float val = row[v];
      s += val;
      s2 += val * val;
    }
  }
#pragma unroll
  for (int off = 32; off > 0; off >>= 1) {
    s += __shfl_down(s, off);
    s2 += __shfl_down(s2, off);
  }
  __shared__ float rs_[4], rs2_[4];
  if ((t & 63) == 0) { rs_[t >> 6] = s; rs2_[t >> 6] = s2; }
  __syncthreads();
  if (t == 0) {
    part[c * 8 + seg] = rs_[0] + rs_[1] + rs_[2] + rs_[3];
    part[128 + c * 8 + seg] = rs2_[0] + rs2_[1] + rs2_[2] + rs2_[3];
  }
}

// ---------------- BN finalize ----------------
__global__ void k_bn_final(const float* __restrict__ part, float* __restrict__ musig) {
  const int c = threadIdx.x;
  if (c < 16) {
    float S = 0.f, S2 = 0.f;
#pragma unroll
    for (int seg = 0; seg < 8; ++seg) {
      S += part[c * 8 + seg];
      S2 += part[128 + c * 8 + seg];
    }
    const float inv = 1.f / 128000.f;
    float mu = S * inv;
    float var = S2 * inv - mu * mu;
    musig[c] = mu;
    musig[16 + c] = rsqrtf(var + 1e-5f);
  }
}

// ---------------- build x0 (normalized, permuted, transposed, scaled 1/16) ----------------
__global__ __launch_bounds__(256) void k_build_x0(const float* __restrict__ x,
                                                  const int* __restrict__ perm,
                                                  const float* __restrict__ musig,
                                                  _Float16* __restrict__ X0) {
  const int idx = blockIdx.x * 256 + threadIdx.x;
  const int v = idx & 4095;
  const int m = idx >> 12;
  const int b = m & 31;
  const int c = m >> 5;
  const int pv = perm[v];
  float val = 0.f;
  if (pv < 4000)
    val = (x[((size_t)(b * 16 + c)) * 4000 + pv] - musig[c]) * musig[16 + c] * 0.0625f;
  X0[idx] = (_Float16)val;
}

// ---------------- f32 -> f16 convert ----------------
__global__ __launch_bounds__(256) void k_cvt_f16(const float* __restrict__ s,
                                                 _Float16* __restrict__ d, int n) {
  const int i = (blockIdx.x * 256 + threadIdx.x) * 4;
  if (i >= n) return;
  f32x4 v = *(const f32x4*)(s + i);
  half4 h;
  h[0] = (_Float16)v[0]; h[1] = (_Float16)v[1];
  h[2] = (_Float16)v[2]; h[3] = (_Float16)v[3];
  *(half4*)(d + i) = h;
}

// ---------------- zero fill ----------------
__global__ __launch_bounds__(256) void k_zero(_Float16* __restrict__ p, int n8) {
  const int i = blockIdx.x * 256 + threadIdx.x;
  if (i < n8) *(half8*)(p + (size_t)i * 8) = half8{};
}

// ---------------- W permute+pad: Wp[f][k*CS + c] = W[f][c*25 + k] ----------------
__global__ __launch_bounds__(256) void k_prep_w(const float* __restrict__ W,
                                                _Float16* __restrict__ Wp,
                                                int F, int shiftC, int kround) {
  const int idx = blockIdx.x * 256 + threadIdx.x;
  const int CS = 1 << shiftC;
  const int KPtot = kround * CS;
  if (idx >= F * KPtot) return;
  const int f = idx / KPtot;
  const int rem = idx - f * KPtot;
  const int k = rem >> shiftC;
  const int c = rem & (CS - 1);
  float v = 0.f;
  if (k < 25) v = W[(size_t)f * (CS * 25) + c * 25 + k];
  Wp[idx] = (_Float16)v;
}

// ---------------- Chebyshev conv1 partial GEMM: 128x128, BK=32, 4-buf / 3-ahead ----------------
// P[kq][m][v] = sum_{u in kq K-slice(1024)} Xprev[m][u] * L[v][u]
// Grid 512 = kq4 x bx32 x by4, 2 blocks/CU. 256 thr = 4 waves (2m x 2v), wave 64x64.
// CHANGE vs R13: 4 LDS buffers (64KB), 3-tiles-ahead staging, counted vmcnt(8) —
// theory: conv1 is L3-latency-bound (per-XCD footprint > 4MB L2); 2-ahead
// (~1.7k cyc) didn't cover ~900cyc+queue L3 latency; 3-ahead (~3.4k cyc) does.
__global__ __launch_bounds__(256, 2) void k_cheb1b(const _Float16* __restrict__ Xprev,
                                                   const _Float16* __restrict__ Lm,
                                                   _Float16* __restrict__ P) {
  __shared__ _Float16 lds[4][8192];  // [buf][A:128x32 (8KB) | B:128x32 (8KB)]
  const int t = threadIdx.x;
  const int lane = t & 63;
  const int ln = lane & 15;
  const int g = lane >> 4;
  const int w = t >> 6;
  const int wm = w >> 1, wn = w & 1;
  const int bid = blockIdx.x;
  const int kq = bid & 3;
  const int bx = (bid >> 2) & 31;
  const int by = bid >> 7;
  const int v0 = bx * 128, m0 = by * 128;
  const size_t rs = 8192;  // 4096 * 2B

  const char* Ag = (const char*)Xprev + (size_t)m0 * rs + kq * 2048;
  const char* Bg = (const char*)Lm + (size_t)v0 * rs + kq * 2048;

  f32x4 acc[4][4] = {};

  auto stage = [&](int buf, int tt) {  // 4 gload_lds / thread
    char* A = (char*)&lds[buf][0];
    char* B = (char*)&lds[buf][4096];
#pragma unroll
    for (int j = 0; j < 2; ++j) {
      const int ch = j * 256 + t;          // 0..511 chunks (128 rows x 4 slots)
      const int row = ch >> 2, c8 = ch & 3;
      const size_t so = (size_t)row * rs + tt * 64 + ((c8 ^ ((row >> 1) & 3)) << 4);
      gload_lds16(Ag + so, A + ch * 16);
      gload_lds16(Bg + so, B + ch * 16);
    }
  };

  // prologue: T0,T1,T2 staged; vmcnt(8) = T0 landed (T1,T2's 8 in flight)
  stage(0, 0);
  stage(1, 1);
  stage(2, 2);
  asm volatile("s_waitcnt vmcnt(8)" ::: "memory");
  asm volatile("s_barrier" ::: "memory");

  for (int tt = 0; tt < 32; ++tt) {
    const int cur = tt & 3;
    const char* A = (const char*)&lds[cur][0];
    const char* B = A + 8192;
    half8 a[4], b[4];
#pragma unroll
    for (int mi = 0; mi < 4; ++mi) {
      const int ar = wm * 64 + mi * 16 + ln;
      a[mi] = *(const half8*)(A + ar * 64 + ((g ^ ((ar >> 1) & 3)) << 4));
    }
#pragma unroll
    for (int ni = 0; ni < 4; ++ni) {
      const int br = wn * 64 + ni * 16 + ln;
      b[ni] = *(const half8*)(B + br * 64 + ((g ^ ((br >> 1) & 3)) << 4));
    }
    if (tt + 3 < 32) {
      stage((tt + 3) & 3, tt + 3);
      asm volatile("s_waitcnt vmcnt(8)" ::: "memory");  // T+1 landed; T+2,T+3 in flight
    } else if (tt + 2 < 32) {
      asm volatile("s_waitcnt vmcnt(4)" ::: "memory");  // T+1 landed; T+2 in flight
    } else {
      asm volatile("s_waitcnt vmcnt(0)" ::: "memory");  // tail drain
    }
    asm volatile("s_barrier" ::: "memory");
    asm volatile("s_waitcnt lgkmcnt(0)" ::: "memory");
    __builtin_amdgcn_sched_barrier(0);
    __builtin_amdgcn_s_setprio(1);
#pragma unroll
    for (int mi = 0; mi < 4; ++mi)
#pragma unroll
      for (int ni = 0; ni < 4; ++ni)
        acc[mi][ni] = __builtin_amdgcn_mfma_f32_16x16x32_f16(a[mi], b[ni], acc[mi][ni], 0, 0, 0);
    __builtin_amdgcn_s_setprio(0);
    asm volatile("s_barrier" ::: "memory");
  }

  // epilogue: write fp16 partial plane kq
  _Float16* Pq = P + (size_t)kq * 2097152;
#pragma unroll
  for (int mi = 0; mi < 4; ++mi) {
#pragma unroll
    for (int ni = 0; ni < 4; ++ni) {
      const int vv = v0 + wn * 64 + ni * 16 + ln;
      const int mmb = m0 + wm * 64 + mi * 16 + g * 4;
#pragma unroll
      for (int r = 0; r < 4; ++r)
        Pq[(size_t)(mmb + r) * 4096 + vv] = (_Float16)acc[mi][ni][r];
    }
  }
}

// ---------------- reduce 4 partials: Xout = alpha*(P0+..+P3) - beta*Xm2 ----------------
__global__ __launch_bounds__(256) void k_cheb_red4(const _Float16* __restrict__ P,
                                                   const _Float16* __restrict__ Xm2,
                                                   _Float16* __restrict__ Xout,
                                                   float alpha, float beta) {
  const size_t i = ((size_t)blockIdx.x * 256 + threadIdx.x) * 8;
  float s[8] = {};
#pragma unroll
  for (int p = 0; p < 4; ++p) {
    half8 v = *(const half8*)(P + (size_t)p * 2097152 + i);
#pragma unroll
    for (int j = 0; j < 8; ++j) s[j] += (float)v[j];
  }
  half8 xm2 = {};
  if (beta != 0.f) xm2 = *(const half8*)(Xm2 + i);
  half8 o;
#pragma unroll
  for (int j = 0; j < 8; ++j) o[j] = (_Float16)(alpha * s[j] - beta * (float)xm2[j]);
  *(half8*)(Xout + i) = o;
}

// ---------------- Chebyshev conv2: fused full-K GEMM (R8, unchanged) ----------------
__global__ __launch_bounds__(256, 2) void k_cheb2(const _Float16* __restrict__ Xprev,
                                                  const _Float16* __restrict__ Lm,
                                                  const _Float16* __restrict__ Xm2,
                                                  _Float16* __restrict__ Xout,
                                                  float alpha, float beta) {
  __shared__ _Float16 lds[3][8192];  // [buf][A:64x64 (8KB) | B:64x64 (8KB)]
  const int t = threadIdx.x;
  const int lane = t & 63;
  const int ln = lane & 15;
  const int g = lane >> 4;
  const int g16 = g << 4;
  const int w = t >> 6;
  const int wm = w >> 1, wn = w & 1;
  const int bx = blockIdx.x & 15;
  const int by = blockIdx.x >> 4;
  const int v0 = bx * 64, m0 = by * 64;
  const size_t rs = 2048;  // 1024 * 2B

  const char* Ag = (const char*)Xprev + (size_t)m0 * rs;
  const char* Bg = (const char*)Lm + (size_t)v0 * rs;

  f32x4 acc[2][2] = {};

  auto stageHalf = [&](int buf, int tt, int half) {  // 2 gload_lds / thread
    const char* src = (half == 0) ? Ag : Bg;
    char* dst0 = (char*)&lds[buf][0] + half * 8192;
#pragma unroll
    for (int j = 0; j < 2; ++j) {
      const int idx = j * 256 + t;
      const int row = idx >> 3, c8 = idx & 7;
      gload_lds16(src + (size_t)row * rs + tt * 128 + ((c8 ^ (row & 7)) << 4),
                  dst0 + idx * 16);
    }
  };

  stageHalf(0, 0, 0); stageHalf(0, 0, 1);
  stageHalf(1, 1, 0); stageHalf(1, 1, 1);
  asm volatile("s_waitcnt vmcnt(4)" ::: "memory");
  asm volatile("s_barrier" ::: "memory");

  for (int tt = 0; tt < 16; ++tt) {
    const int cur = tt % 3;
    const int nxt = (tt + 2) % 3;
    const char* A = (const char*)&lds[cur][0];
    const char* B = A + 8192;
    half8 a[2][2], b[2][2];
#pragma unroll
    for (int kk = 0; kk < 2; ++kk) {
#pragma unroll
      for (int mi = 0; mi < 2; ++mi) {
        const int ar = wm * 32 + mi * 16 + ln;
        a[kk][mi] = *(const half8*)(A + ar * 128 + ((kk * 64 + g16) ^ ((ar & 7) << 4)));
      }
#pragma unroll
      for (int ni = 0; ni < 2; ++ni) {
        const int br = wn * 32 + ni * 16 + ln;
        b[kk][ni] = *(const half8*)(B + br * 128 + ((kk * 64 + g16) ^ ((br & 7) << 4)));
      }
    }
    if (tt + 2 < 16) {
      stageHalf(nxt, tt + 2, 0);
      stageHalf(nxt, tt + 2, 1);
      asm volatile("s_waitcnt vmcnt(4)" ::: "memory");
    } else {
      asm volatile("s_waitcnt vmcnt(0)" ::: "memory");
    }
    asm volatile("s_barrier" ::: "memory");
    asm volatile("s_waitcnt lgkmcnt(0)" ::: "memory");
    __builtin_amdgcn_sched_barrier(0);
    __builtin_amdgcn_s_setprio(1);
#pragma unroll
    for (int kk = 0; kk < 2; ++kk)
#pragma unroll
      for (int mi = 0; mi < 2; ++mi)
#pragma unroll
        for (int ni = 0; ni < 2; ++ni)
          acc[mi][ni] = __builtin_amdgcn_mfma_f32_16x16x32_f16(a[kk][mi], b[kk][ni],
                                                               acc[mi][ni], 0, 0, 0);
    __builtin_amdgcn_s_setprio(0);
    asm volatile("s_barrier" ::: "memory");
  }

#pragma unroll
  for (int mi = 0; mi < 2; ++mi) {
#pragma unroll
    for (int ni = 0; ni < 2; ++ni) {
      const int vv = v0 + wn * 32 + ni * 16 + ln;
      const int mmb = m0 + wm * 32 + mi * 16 + g * 4;
#pragma unroll
      for (int r = 0; r < 4; ++r) {
        const size_t idx = (size_t)(mmb + r) * 1024 + vv;
        float val = alpha * acc[mi][ni][r];
        if (beta != 0.f) val -= (float)Xm2[idx];
        Xout[idx] = (_Float16)val;
      }
    }
  }
}

// ---------------- Dense projection GEMM + FUSED maxpool4 epilogue ----------------
// MODE 1 (conv1 dense): pooled fp16 out, scale 1/64, to Xpool[(f*32+b)*1024 + v/4]
// MODE 2 (conv2 dense): pooled f32 out to p2[b*32768 + f*256 + v/4]
// k==0 B-slice remapped to plane k0plane (dense2 reads pooled X2 at plane 28).
template <int FT, int MODE>
__global__ __launch_bounds__(256, 2) void k_dense(const _Float16* __restrict__ Wp,
                                                  const _Float16* __restrict__ XS,
                                                  const float* __restrict__ bias,
                                                  void* __restrict__ outp,
                                                  int Vv, int shiftC, int nsteps,
                                                  int k0plane, float ascale, float bscale) {
  __shared__ _Float16 Alds[2][FT * 64];
  __shared__ _Float16 Blds[2][64 * 64];
  const int t = threadIdx.x;
  const int lane = t & 63;
  const int g = lane >> 4;
  const int w = t >> 6;
  const int n0 = blockIdx.x * 64;
  const int b = n0 / Vv;
  const int vb = n0 % Vv;
  const int Kp = nsteps * 64;
  const int cmask = (1 << shiftC) - 1;
  const size_t plane = 2097152;

  f32x4 acc[FT / 16] = {};

  auto stage = [&](int buf, int s) {
    const int q0 = s * 64;
    char* A = (char*)&Alds[buf][0];
    char* B = (char*)&Blds[buf][0];
#pragma unroll
    for (int j = 0; j < FT / 32; ++j) {
      const int ch = j * 256 + t;
      const int f = ch >> 3, c8 = ch & 7;
      gload_lds16((const char*)Wp + ((size_t)f * Kp + q0) * 2 + ((c8 ^ (f & 7)) << 4),
                  A + ch * 16);
    }
#pragma unroll
    for (int j = 0; j < 2; ++j) {
      const int ch = j * 256 + t;
      const int q = ch >> 3, c8 = ch & 7;
      const int qq = q0 + q;
      int k = qq >> shiftC;
      const int c = qq & cmask;
      if (k == 0) k = k0plane;
      const int sz = (q >> 3) & 7;
      gload_lds16((const char*)XS + ((size_t)k * plane + (size_t)(c * 32 + b) * Vv + vb) * 2 +
                      ((c8 ^ sz) << 4),
                  B + ch * 16);
    }
  };

  stage(0, 0);

  for (int s = 0; s < nsteps; ++s) {
    const int cur = s & 1;
    if (s + 1 < nsteps) {
      stage(cur ^ 1, s + 1);
      if constexpr (FT == 64) {
        asm volatile("s_waitcnt vmcnt(4)" ::: "memory");
      } else {
        asm volatile("s_waitcnt vmcnt(6)" ::: "memory");
      }
    } else {
      asm volatile("s_waitcnt vmcnt(0)" ::: "memory");
    }
    asm volatile("s_barrier" ::: "memory");
    const _Float16* A = &Alds[cur][0];
    const _Float16* B = &Blds[cur][0];
#pragma unroll
    for (int kk = 0; kk < 2; ++kk) {
      half8 bf;
      const int c = lane & 15;
#pragma unroll
      for (int j = 0; j < 8; ++j) {
        const int q = kk * 32 + g * 8 + j;
        const int sz = (q >> 3) & 7;
        bf[j] = B[q * 64 + ((w * 16 + c) ^ (sz << 3))];
      }
#pragma unroll
      for (int mi = 0; mi < FT / 16; ++mi) {
        const int ar = mi * 16 + c;
        half8 af = *(const half8*)((const char*)A + ar * 128 +
                                   ((kk * 64 + g * 16) ^ ((ar & 7) << 4)));
        acc[mi] = __builtin_amdgcn_mfma_f32_16x16x32_f16(af, bf, acc[mi], 0, 0, 0);
      }
    }
    asm volatile("s_barrier" ::: "memory");
  }

  // fused epilogue: relu(ascale*acc + bscale*bias) -> maxpool4 over v (lane groups)
  const int v = vb + w * 16 + (lane & 15);  // local v in batch b
  const bool writer = (lane & 3) == 0;
#pragma unroll
  for (int mi = 0; mi < FT / 16; ++mi) {
#pragma unroll
    for (int r = 0; r < 4; ++r) {
      const int f = mi * 16 + g * 4 + r;
      float val = fmaxf(ascale * acc[mi][r] + bscale * bias[f], 0.f);
      val = fmaxf(val, __shfl_xor(val, 1));
      val = fmaxf(val, __shfl_xor(val, 2));
      if (writer) {
        if constexpr (MODE == 1) {
          _Float16* Xp = (_Float16*)outp;
          Xp[(size_t)(f * 32 + b) * 1024 + (v >> 2)] = (_Float16)(val * 0.015625f);
        } else {
          float* p2 = (float*)outp;
          p2[(size_t)b * 32768 + f * 256 + (v >> 2)] = val;
        }
      }
    }
  }
}

// ---------------- FC pass 1 ----------------
__global__ __launch_bounds__(256) void k_fc_part(const float* __restrict__ p2,
                                                 const float* __restrict__ Wfc,
                                                 float* __restrict__ partF) {
  const int b = blockIdx.x >> 3;
  const int seg = blockIdx.x & 7;
  const int t = threadIdx.x;
  const int lane = t & 63;
  const int w = t >> 6;
  const int base = seg * 4096;
  float acc[10];
#pragma unroll
  for (int o = 0; o < 10; ++o) acc[o] = 0.f;
  const float* pb = p2 + (size_t)b * 32768 + base;
  for (int i = t; i < 4096; i += 256) {
    float p = pb[i];
#pragma unroll
    for (int o = 0; o < 10; ++o) acc[o] += p * Wfc[(size_t)o * 32768 + base + i];
  }
#pragma unroll
  for (int off = 32; off > 0; off >>= 1)
#pragma unroll
    for (int o = 0; o < 10; ++o) acc[o] += __shfl_down(acc[o], off);
  __shared__ float rws[10][4];
  if (lane == 0) {
#pragma unroll
    for (int o = 0; o < 10; ++o) rws[o][w] = acc[o];
  }
  __syncthreads();
  if (t < 10) partF[blockIdx.x * 10 + t] =
      rws[t][0] + rws[t][1] + rws[t][2] + rws[t][3];
}

// ---------------- FC pass 2 ----------------
__global__ void k_fc_final(const float* __restrict__ partF,
                           const float* __restrict__ bfc,
                           float* __restrict__ out) {
  const int t = threadIdx.x;
  if (t < 320) {
    const int b = t / 10, o = t - b * 10;
    float s = 0.f;
#pragma unroll
    for (int seg = 0; seg < 8; ++seg) s += partF[(b * 8 + seg) * 10 + o];
    out[b * 10 + o] = 64.f * s + bfc[o];
  }
}

extern "C" void kernel_launch(void* const* d_in, const int* in_sizes, int n_in,
                              void* d_out, int out_size, void* d_ws, size_t ws_size,
                              hipStream_t stream) {
  (void)in_sizes; (void)n_in; (void)out_size; (void)ws_size;
  const float* x = (const float*)d_in[0];
  const int* perm = (const int*)d_in[1];
  const float* L1 = (const float*)d_in[2];
  const float* L2 = (const float*)d_in[3];
  const float* W1 = (const float*)d_in[4];
  const float* b1 = (const float*)d_in[5];
  const float* W2 = (const float*)d_in[6];
  const float* b2 = (const float*)d_in[7];
  const float* Wfc = (const float*)d_in[8];
  const float* bfc = (const float*)d_in[9];
  float* out = (float*)d_out;

  char* ws = (char*)d_ws;
  size_t off = 0;
  auto alloc = [&](size_t bytes) {
    char* p = ws + off;
    off += (bytes + 255) & ~(size_t)255;
    return p;
  };
  _Float16* L1h = (_Float16*)alloc(16777216ull * 2);
  _Float16* L2h = (_Float16*)alloc(1048576ull * 2);
  _Float16* W1p = (_Float16*)alloc(64ull * 448 * 2);
  _Float16* W2p = (_Float16*)alloc(128ull * 1664 * 2);
  float* part = (float*)alloc(256 * 4);
  float* musig = (float*)alloc(32 * 4);
  float* partF = (float*)alloc(2560 * 4);
  _Float16* XS = (_Float16*)alloc(29ull * 2097152 * 2);   // 25 states + 3 zero + 1 pooled
  float* Yt = (float*)alloc(64ull * 131072 * 4);          // Pq alias (16MB used)
  float* p2 = (float*)alloc(32ull * 128 * 256 * 4);
  _Float16* Pq = (_Float16*)Yt;  // 4 partial planes (16MB)

  const size_t plane = 2097152;

  k_cvt_f16<<<16384, 256, 0, stream>>>(L1, L1h, 16777216);
  k_cvt_f16<<<1024, 256, 0, stream>>>(L2, L2h, 1048576);
  k_prep_w<<<112, 256, 0, stream>>>(W1, W1p, 64, 4, 28);
  k_prep_w<<<832, 256, 0, stream>>>(W2, W2p, 128, 6, 26);
  k_zero<<<3072, 256, 0, stream>>>(XS + 25 * plane, 786432);  // zero planes 25..27
  k_bn_partial<<<128, 256, 0, stream>>>(x, part);
  k_bn_final<<<1, 64, 0, stream>>>(part, musig);
  k_build_x0<<<8192, 256, 0, stream>>>(x, perm, musig, XS);

  // conv1: grid 512 = kq4 x bx32 x by4 -> 2 blocks/CU, 4-buf/3-ahead pipeline
  for (int k = 1; k < 25; ++k) {
    k_cheb1b<<<512, 256, 0, stream>>>(XS + (size_t)(k - 1) * plane, L1h, Pq);
    k_cheb_red4<<<1024, 256, 0, stream>>>(
        Pq, XS + (size_t)(k >= 2 ? k - 2 : 0) * plane, XS + (size_t)k * plane,
        (k == 1) ? 1.f : 2.f, (k == 1) ? 0.f : 1.f);
  }
  // dense1 + fused pool1 -> pooled X2_0 at plane 28
  k_dense<64, 1><<<dim3(2048, 1), 256, 0, stream>>>(W1p, XS, b1, XS + 28 * plane,
                                                    4096, 4, 7, 0, 16.f, 1.f);
  // conv2: plane28 holds X2_0; states k=1..24 at planes 1..24
  auto Xp = [&](int k) { return XS + (size_t)((k == 0) ? 28 : k) * plane; };
  for (int k = 1; k < 25; ++k) {
    k_cheb2<<<512, 256, 0, stream>>>(
        Xp(k - 1), L2h, Xp(k >= 2 ? k - 2 : 0), Xp(k),
        (k == 1) ? 1.f : 2.f, (k == 1) ? 0.f : 1.f);
  }
  // dense2 + fused pool2 -> p2 (k==0 B-slice remapped to plane 28)
  k_dense<128, 2><<<dim3(512, 1), 256, 0, stream>>>(W2p, XS, b2, p2,
                                                    1024, 6, 26, 28, 1.f, 0.015625f);
  k_fc_part<<<256, 256, 0, stream>>>(p2, Wfc, partF);
  k_fc_final<<<1, 320, 0, stream>>>(partF, bfc, out);
}